// Round 4
// baseline (1180.286 us; speedup 1.0000x reference)
//
#include <hip/hip_runtime.h>

// ---------------------------------------------------------------------------
// Hetero-SAGE edge classifier.
//  Round-4: XCD-owned partitioned scatter. Round-3 post-mortem: banding the
//  write window doesn't help because all 8 XCDs still co-write every 64B
//  line (per-XCD L2s write back partial lines separately -> 13x HBM write
//  amplification). Fix: partition the DEST NODE SPACE 8 ways; block
//  (p=blockIdx&7, chunk=blockIdx>>3) reads chunk c but only scatters edges
//  whose dest is in partition p. With round-robin blockIdx->XCD dispatch,
//  each CSR line has a single writing XCD -> merges in that L2, retires once.
//  csr_u packed as int2 (src,eid): one 8B store per edge, one window.
// ---------------------------------------------------------------------------

__device__ inline unsigned short f2bf(float f) {
  unsigned u = __float_as_uint(f);
  u += 0x7FFF + ((u >> 16) & 1);  // round-to-nearest-even
  return (unsigned short)(u >> 16);
}
__device__ inline float bf2f(unsigned short h) {
  return __uint_as_float(((unsigned)h) << 16);
}

__global__ void tobf16(const float* __restrict__ in, unsigned short* __restrict__ out, int n4) {
  int i = blockIdx.x * 256 + threadIdx.x;
  int stride = gridDim.x * 256;
  for (int j = i; j < n4; j += stride) {
    float4 v = reinterpret_cast<const float4*>(in)[j];
    ushort4 o;
    o.x = f2bf(v.x); o.y = f2bf(v.y); o.z = f2bf(v.z); o.w = f2bf(v.w);
    reinterpret_cast<ushort4*>(out)[j] = o;
  }
}

__global__ void hist_kernel(const int* __restrict__ u_idx, const int* __restrict__ m_idx,
                            int* __restrict__ cnt_u, int* __restrict__ cnt_m, int E) {
  int e = blockIdx.x * 256 + threadIdx.x;
  if (e < E) {
    atomicAdd(&cnt_u[u_idx[e]], 1);
    atomicAdd(&cnt_m[m_idx[e]], 1);
  }
}

// ---- 3-phase exclusive scan (chunk = 2048 = 256 threads * 8 items) --------
__global__ void scanA(const int* __restrict__ cnt, int* __restrict__ off,
                      int* __restrict__ part, int N) {
  __shared__ int s[256];
  int t = threadIdx.x;
  int base = blockIdx.x * 2048 + t * 8;
  int v[8]; int sum = 0;
#pragma unroll
  for (int i = 0; i < 8; ++i) { int idx = base + i; v[i] = (idx < N) ? cnt[idx] : 0; sum += v[i]; }
  s[t] = sum;
  __syncthreads();
  for (int ofs = 1; ofs < 256; ofs <<= 1) {
    int a = (t >= ofs) ? s[t - ofs] : 0;
    __syncthreads();
    s[t] += a;
    __syncthreads();
  }
  int run = s[t] - sum;
#pragma unroll
  for (int i = 0; i < 8; ++i) { int idx = base + i; if (idx < N) off[idx] = run; run += v[i]; }
  if (t == 255) part[blockIdx.x] = s[255];
}

__global__ void scanB(int* __restrict__ part, int* __restrict__ off_last, int NB) {
  __shared__ int s[256];
  int t = threadIdx.x;
  int v = (t < NB) ? part[t] : 0;
  s[t] = v;
  __syncthreads();
  for (int ofs = 1; ofs < 256; ofs <<= 1) {
    int a = (t >= ofs) ? s[t - ofs] : 0;
    __syncthreads();
    s[t] += a;
    __syncthreads();
  }
  if (t < NB) part[t] = s[t] - v;
  if (t == NB - 1) off_last[0] = s[t];
}

__global__ void scanC(int* __restrict__ off, const int* __restrict__ part, int N) {
  int base = blockIdx.x * 2048 + threadIdx.x * 8;
  int add = part[blockIdx.x];
#pragma unroll
  for (int i = 0; i < 8; ++i) { int idx = base + i; if (idx < N) off[idx] += add; }
}

// ---- XCD-owned partitioned scatter ----------------------------------------
// 8 partitions of the dest-node space; block (p,c) reads edge chunk c and
// scatters only edges whose destination maps to partition p. All writers of
// a CSR line share one XCD (heuristic blockIdx&7 -> XCD) -> line-merge in L2.
__global__ __launch_bounds__(256) void scatter_part(
    const int* __restrict__ u_idx, const int* __restrict__ m_idx,
    const int* __restrict__ off_u, const int* __restrict__ off_m,
    int* __restrict__ cur_u, int* __restrict__ cur_m,
    int2* __restrict__ csr_u, int* __restrict__ csr_m_src,
    int E, float scale_u, float scale_m) {
  int part = blockIdx.x & 7;
  int chunk = blockIdx.x >> 3;
  int e0 = chunk * 2048 + threadIdx.x;
#pragma unroll
  for (int i = 0; i < 8; ++i) {
    int e = e0 + i * 256;  // coalesced per i
    if (e < E) {
      int u = __builtin_nontemporal_load(&u_idx[e]);
      int m = __builtin_nontemporal_load(&m_idx[e]);
      int pu = (int)((float)u * scale_u);  // any deterministic u->0..7 map works
      if (pu == part) {
        int pos = off_u[u] + atomicAdd(&cur_u[u], 1);
        csr_u[pos] = make_int2(m, e);
      }
      int pm = (int)((float)m * scale_m);
      if (pm == part) {
        int pos = off_m[m] + atomicAdd(&cur_m[m], 1);
        csr_m_src[pos] = u;
      }
    }
  }
}

// ---- weight preparation ---------------------------------------------------
// Wcat layout: [128][64] row-major; rows 0..63 aggregate weight, 64..127 root.
__global__ void mkW1(const float* __restrict__ bases1, const float* __restrict__ coeff1,
                     const float* __restrict__ root1,
                     const float* __restrict__ bases2, const float* __restrict__ coeff2,
                     float* __restrict__ Wcat1u, float* __restrict__ Wcat1m,
                     float* __restrict__ wp2, float* __restrict__ wr2) {
  int ij = blockIdx.x * 256 + threadIdx.x;  // 0..4095
  float a0 = bases1[ij], a1 = bases1[4096 + ij], a2 = bases1[8192 + ij];
  Wcat1m[ij] = coeff1[0] * a0 + coeff1[1] * a1 + coeff1[2] * a2;  // W_pays1
  Wcat1u[ij] = coeff1[3] * a0 + coeff1[4] * a1 + coeff1[5] * a2;  // W_rev1
  float r = root1[ij];
  Wcat1m[4096 + ij] = r;
  Wcat1u[4096 + ij] = r;
  float c0 = bases2[ij], c1 = bases2[4096 + ij], c2 = bases2[8192 + ij];
  wp2[ij] = coeff2[0] * c0 + coeff2[1] * c1 + coeff2[2] * c2;
  wr2[ij] = coeff2[3] * c0 + coeff2[4] * c1 + coeff2[5] * c2;
}

__global__ void mkW2(const float* __restrict__ wp2, const float* __restrict__ wr2,
                     const float* __restrict__ root2, const float* __restrict__ w_mlp1,
                     const float* __restrict__ b2, const float* __restrict__ b_mlp1,
                     float* __restrict__ Wcat2u, float* __restrict__ Wcat2m,
                     float* __restrict__ bu2, float* __restrict__ bm2) {
  int tid = blockIdx.x * 256 + threadIdx.x;  // 0..4095
  int i = tid >> 6, j = tid & 63;
  float au = 0.f, ru = 0.f, am = 0.f, rm = 0.f;
  for (int k = 0; k < 64; ++k) {
    float wa = w_mlp1[k * 64 + j];
    float wb = w_mlp1[(64 + k) * 64 + j];
    au += wr2[i * 64 + k] * wa;
    ru += root2[i * 64 + k] * wa;
    am += wp2[i * 64 + k] * wb;
    rm += root2[i * 64 + k] * wb;
  }
  Wcat2u[tid] = au; Wcat2u[4096 + tid] = ru;
  Wcat2m[tid] = am; Wcat2m[4096 + tid] = rm;
  if (i == 0) {
    float s1 = 0.f, s2 = 0.f;
    for (int k = 0; k < 64; ++k) {
      s1 += b2[k] * w_mlp1[k * 64 + j];
      s2 += b2[k] * w_mlp1[(64 + k) * 64 + j];
    }
    bu2[j] = s1;
    bm2[j] = s2 + b_mlp1[j];
  }
}

// ---- fused segment-mean + [agg|self] @ Wcat + bias (+relu) ----------------
// block = 256 = 4 waves; each wave owns 8 nodes; lane = feature.
// CSTRIDE: csr entry stride in ints (2 for int2-packed CSR-u, 1 for CSR-m).
template <int CSTRIDE, int SELF_F32, int RELU>
__global__ __launch_bounds__(256) void agg_tf(
    const unsigned short* __restrict__ src,   // [Ns][64] bf16
    const void* __restrict__ selfF,           // [N][64] f32 or bf16
    const int* __restrict__ off, const int* __restrict__ csr,
    const float* __restrict__ W,              // [128][64]
    const float* __restrict__ bias,           // [64]
    unsigned short* __restrict__ out, int N) {
  __shared__ float sv[4][8][128];  // [wave][node][agg|self]
  int t = threadIdx.x, wave = t >> 6, lane = t & 63;
  int nbase = (blockIdx.x * 4 + wave) * 8;
  if (nbase >= N) return;  // whole-wave early out (no cross-wave deps)
  float b = bias[lane];
#pragma unroll
  for (int g = 0; g < 8; ++g) {
    int n = nbase + g;
    float a = 0.f, sf = 0.f;
    if (n < N) {
      int beg = off[n], end = off[n + 1], k = beg;
      for (; k + 4 <= end; k += 4) {
        int s0 = csr[(size_t)k * CSTRIDE];
        int s1 = csr[(size_t)(k + 1) * CSTRIDE];
        int s2 = csr[(size_t)(k + 2) * CSTRIDE];
        int s3 = csr[(size_t)(k + 3) * CSTRIDE];
        float a0 = bf2f(src[(size_t)s0 * 64 + lane]);
        float a1 = bf2f(src[(size_t)s1 * 64 + lane]);
        float a2 = bf2f(src[(size_t)s2 * 64 + lane]);
        float a3 = bf2f(src[(size_t)s3 * 64 + lane]);
        a += (a0 + a1) + (a2 + a3);
      }
      for (; k < end; ++k) a += bf2f(src[(size_t)csr[(size_t)k * CSTRIDE] * 64 + lane]);
      a /= fmaxf((float)(end - beg), 1.f);  // segment mean (0 if empty)
      sf = SELF_F32 ? ((const float*)selfF)[(size_t)n * 64 + lane]
                    : bf2f(((const unsigned short*)selfF)[(size_t)n * 64 + lane]);
    }
    sv[wave][g][lane] = a;
    sv[wave][g][64 + lane] = sf;
  }
  // wave-local LDS: compiler's lgkmcnt ordering suffices, no barrier
  float o[8];
#pragma unroll
  for (int g = 0; g < 8; ++g) o[g] = b;
#pragma unroll 4
  for (int k = 0; k < 128; ++k) {
    float w = W[k * 64 + lane];  // coalesced 256B, same addrs all waves -> cache broadcast
#pragma unroll
    for (int g = 0; g < 8; ++g) o[g] += sv[wave][g][k] * w;
  }
#pragma unroll
  for (int g = 0; g < 8; ++g) {
    int n = nbase + g;
    if (n < N) {
      float v = o[g];
      if (RELU) v = fmaxf(v, 0.f);
      out[(size_t)n * 64 + lane] = f2bf(v);
    }
  }
}

// ---- edge classifier, CSR-ordered -----------------------------------------
// logits[eid] = relu(pu[u]+pm[m]) @ w_mlp2 + b_mlp2
// wave per user; 4 subgroups of 16 lanes -> 4 edges per iteration;
// lane covers 4 features (ushort4 = 8B; 16 lanes = one 128B bf16 row).
__global__ __launch_bounds__(256) void edge_mlp(
    const unsigned short* __restrict__ pu, const unsigned short* __restrict__ pm,
    const int* __restrict__ off_u, const int2* __restrict__ csr_u,
    const float* __restrict__ w2, const float* __restrict__ bvec,
    float* __restrict__ out, int Nu) {
  int t = threadIdx.x;
  int lane = t & 63;
  int sub = lane >> 4;   // subgroup 0..3
  int fl = lane & 15;    // position in subgroup
  int f = fl * 4;        // features f..f+3
  int wid = (blockIdx.x * 256 + t) >> 6;
  int nw = (gridDim.x * 256) >> 6;
  // w2 is [64][2]; float4 j covers rows 2j,2j+1
  float4 wA = reinterpret_cast<const float4*>(w2)[2 * fl];      // rows f, f+1
  float4 wB = reinterpret_cast<const float4*>(w2)[2 * fl + 1];  // rows f+2, f+3
  float ob0 = bvec[0], ob1 = bvec[1];
  for (int u = wid; u < Nu; u += nw) {
    int beg = off_u[u], end = off_u[u + 1];
    if (beg == end) continue;
    ushort4 p4 = *reinterpret_cast<const ushort4*>(&pu[(size_t)u * 64 + f]);
    float pu0 = bf2f(p4.x), pu1 = bf2f(p4.y), pu2 = bf2f(p4.z), pu3 = bf2f(p4.w);
    for (int k = beg; k < end; k += 4) {
      int e = k + sub;
      bool valid = e < end;
      int2 se = csr_u[valid ? e : beg];
      ushort4 v4 = *reinterpret_cast<const ushort4*>(&pm[(size_t)se.x * 64 + f]);
      float v0 = fmaxf(pu0 + bf2f(v4.x), 0.f);
      float v1 = fmaxf(pu1 + bf2f(v4.y), 0.f);
      float v2 = fmaxf(pu2 + bf2f(v4.z), 0.f);
      float v3 = fmaxf(pu3 + bf2f(v4.w), 0.f);
      float a0 = v0 * wA.x + v1 * wA.z + v2 * wB.x + v3 * wB.z;
      float a1 = v0 * wA.y + v1 * wA.w + v2 * wB.y + v3 * wB.w;
#pragma unroll
      for (int o = 8; o; o >>= 1) { a0 += __shfl_xor(a0, o); a1 += __shfl_xor(a1, o); }
      if (valid && fl == 0) {
        *reinterpret_cast<float2*>(&out[(size_t)se.y * 2]) =
            make_float2(a0 + ob0, a1 + ob1);
      }
    }
  }
}

extern "C" void kernel_launch(void* const* d_in, const int* in_sizes, int n_in,
                              void* d_out, int out_size, void* d_ws, size_t ws_size,
                              hipStream_t stream) {
  const float* x_user  = (const float*)d_in[0];
  const float* x_merch = (const float*)d_in[1];
  const float* bases1  = (const float*)d_in[2];
  const float* coeff1  = (const float*)d_in[3];
  const float* root1   = (const float*)d_in[4];
  const float* b1      = (const float*)d_in[5];
  const float* bases2  = (const float*)d_in[6];
  const float* coeff2  = (const float*)d_in[7];
  const float* root2   = (const float*)d_in[8];
  const float* b2      = (const float*)d_in[9];
  const float* w_mlp1  = (const float*)d_in[10];
  const float* b_mlp1  = (const float*)d_in[11];
  const float* w_mlp2  = (const float*)d_in[12];
  const float* b_mlp2  = (const float*)d_in[13];
  const int*   edge_ix = (const int*)d_in[14];

  const int Nu = in_sizes[0] / 64;
  const int Nm = in_sizes[1] / 64;
  const int E  = in_sizes[14] / 2;
  const int* u_idx = edge_ix;
  const int* m_idx = edge_ix + E;

  char* p = (char*)d_ws;
  auto alloc = [&](size_t bytes) -> char* {
    char* r = p;
    p += (bytes + 255) & ~(size_t)255;
    return r;
  };
  int* off_u = (int*)alloc((size_t)(Nu + 1) * 4);
  int* off_m = (int*)alloc((size_t)(Nm + 1) * 4);
  int* zero_base = (int*)alloc((size_t)(2 * Nu + 2 * Nm) * 4);
  int* cnt_u = zero_base;
  int* cnt_m = zero_base + Nu;
  int* cur_u = zero_base + Nu + Nm;
  int* cur_m = zero_base + 2 * Nu + Nm;
  int* part_u = (int*)alloc(256 * 4);
  int* part_m = (int*)alloc(256 * 4);
  int2* csr_u = (int2*)alloc((size_t)E * 8);     // (src merchant, eid)
  int* csr_m_src = (int*)alloc((size_t)E * 4);
  unsigned short* xb_u = (unsigned short*)alloc((size_t)Nu * 64 * 2);  // later reused as pu
  unsigned short* xb_m = (unsigned short*)alloc((size_t)Nm * 64 * 2);  // later reused as pm
  unsigned short* h_u  = (unsigned short*)alloc((size_t)Nu * 64 * 2);
  unsigned short* h_m  = (unsigned short*)alloc((size_t)Nm * 64 * 2);
  float* Wcat1u = (float*)alloc(8192 * 4);
  float* Wcat1m = (float*)alloc(8192 * 4);
  float* Wcat2u = (float*)alloc(8192 * 4);
  float* Wcat2m = (float*)alloc(8192 * 4);
  float* wp2 = (float*)alloc(4096 * 4);
  float* wr2 = (float*)alloc(4096 * 4);
  float* bu2 = (float*)alloc(64 * 4);
  float* bm2 = (float*)alloc(64 * 4);
  if ((size_t)(p - (char*)d_ws) > ws_size) return;

  hipMemsetAsync(zero_base, 0, (size_t)(2 * Nu + 2 * Nm) * 4, stream);

  int ebl = (E + 255) / 256;
  hist_kernel<<<ebl, 256, 0, stream>>>(u_idx, m_idx, cnt_u, cnt_m, E);

  int nbu = (Nu + 2047) / 2048, nbm = (Nm + 2047) / 2048;
  scanA<<<nbu, 256, 0, stream>>>(cnt_u, off_u, part_u, Nu);
  scanB<<<1, 256, 0, stream>>>(part_u, off_u + Nu, nbu);
  scanC<<<nbu, 256, 0, stream>>>(off_u, part_u, Nu);
  scanA<<<nbm, 256, 0, stream>>>(cnt_m, off_m, part_m, Nm);
  scanB<<<1, 256, 0, stream>>>(part_m, off_m + Nm, nbm);
  scanC<<<nbm, 256, 0, stream>>>(off_m, part_m, Nm);

  // 8 partition-owned passes: block (p=blockIdx&7, chunk=blockIdx>>3)
  int nchunk = (E + 2047) / 2048;
  float scale_u = 8.0f / (float)Nu * (1.0f - 1e-7f);  // maps u -> 0..7
  float scale_m = 8.0f / (float)Nm * (1.0f - 1e-7f);
  scatter_part<<<8 * nchunk, 256, 0, stream>>>(u_idx, m_idx, off_u, off_m,
                                               cur_u, cur_m, csr_u, csr_m_src,
                                               E, scale_u, scale_m);

  tobf16<<<1024, 256, 0, stream>>>(x_user, xb_u, Nu * 16);
  tobf16<<<256, 256, 0, stream>>>(x_merch, xb_m, Nm * 16);

  mkW1<<<16, 256, 0, stream>>>(bases1, coeff1, root1, bases2, coeff2,
                               Wcat1u, Wcat1m, wp2, wr2);
  mkW2<<<16, 256, 0, stream>>>(wp2, wr2, root2, w_mlp1, b2, b_mlp1,
                               Wcat2u, Wcat2m, bu2, bm2);

  int gbu = (Nu + 31) / 32, gbm = (Nm + 31) / 32;
  // layer 1 (relu): self from original f32 arrays
  agg_tf<2, 1, 1><<<gbu, 256, 0, stream>>>(xb_m, x_user, off_u, (const int*)csr_u,
                                           Wcat1u, b1, h_u, Nu);
  agg_tf<1, 1, 1><<<gbm, 256, 0, stream>>>(xb_u, x_merch, off_m, csr_m_src,
                                           Wcat1m, b1, h_m, Nm);
  // layer 2 fused with edge-MLP left matrix; outputs reuse xb buffers
  unsigned short* pm_buf = xb_m;  // xb_m last read by layer-1 user agg (done)
  unsigned short* pu_buf = xb_u;  // xb_u last read by layer-1 merch agg (done)
  agg_tf<1, 0, 0><<<gbm, 256, 0, stream>>>(h_u, h_m, off_m, csr_m_src,
                                           Wcat2m, bm2, pm_buf, Nm);
  agg_tf<2, 0, 0><<<gbu, 256, 0, stream>>>(h_m, h_u, off_u, (const int*)csr_u,
                                           Wcat2u, bu2, pu_buf, Nu);

  edge_mlp<<<2048, 256, 0, stream>>>(pu_buf, pm_buf, off_u, csr_u,
                                     w_mlp2, b_mlp2, (float*)d_out, Nu);
}

// Round 5
// 1113.219 us; speedup vs baseline: 1.0602x; 1.0602x over previous
//
#include <hip/hip_runtime.h>

// ---------------------------------------------------------------------------
// Hetero-SAGE edge classifier.
//  Round-5: (a) PERSISTENT XCD-owned scatter — exactly 2048 blocks (8/CU x
//  256 CU) so all blocks are resident from t=0 and the blockIdx&7 -> XCD
//  round-robin mapping cannot decay; partition p's CSR window is written by
//  one XCD only -> 64B lines merge in that L2. Round-4 failed because its
//  7816-block grid remapped blocks to free XCDs after the first wave.
//  (b) edge_mlp back to EDGE ORDER: output writes coalesced (CSR-ordered
//  version scatter-wrote out[eid], re-amplifying 16MB to ~100MB+); CSR
//  entries shrink to one int (src only).
// ---------------------------------------------------------------------------

__device__ inline unsigned short f2bf(float f) {
  unsigned u = __float_as_uint(f);
  u += 0x7FFF + ((u >> 16) & 1);  // round-to-nearest-even
  return (unsigned short)(u >> 16);
}
__device__ inline float bf2f(unsigned short h) {
  return __uint_as_float(((unsigned)h) << 16);
}

__global__ void tobf16(const float* __restrict__ in, unsigned short* __restrict__ out, int n4) {
  int i = blockIdx.x * 256 + threadIdx.x;
  int stride = gridDim.x * 256;
  for (int j = i; j < n4; j += stride) {
    float4 v = reinterpret_cast<const float4*>(in)[j];
    ushort4 o;
    o.x = f2bf(v.x); o.y = f2bf(v.y); o.z = f2bf(v.z); o.w = f2bf(v.w);
    reinterpret_cast<ushort4*>(out)[j] = o;
  }
}

__global__ void hist_kernel(const int* __restrict__ u_idx, const int* __restrict__ m_idx,
                            int* __restrict__ cnt_u, int* __restrict__ cnt_m, int E) {
  int e = blockIdx.x * 256 + threadIdx.x;
  if (e < E) {
    atomicAdd(&cnt_u[u_idx[e]], 1);
    atomicAdd(&cnt_m[m_idx[e]], 1);
  }
}

// ---- 3-phase exclusive scan (chunk = 2048 = 256 threads * 8 items) --------
__global__ void scanA(const int* __restrict__ cnt, int* __restrict__ off,
                      int* __restrict__ part, int N) {
  __shared__ int s[256];
  int t = threadIdx.x;
  int base = blockIdx.x * 2048 + t * 8;
  int v[8]; int sum = 0;
#pragma unroll
  for (int i = 0; i < 8; ++i) { int idx = base + i; v[i] = (idx < N) ? cnt[idx] : 0; sum += v[i]; }
  s[t] = sum;
  __syncthreads();
  for (int ofs = 1; ofs < 256; ofs <<= 1) {
    int a = (t >= ofs) ? s[t - ofs] : 0;
    __syncthreads();
    s[t] += a;
    __syncthreads();
  }
  int run = s[t] - sum;
#pragma unroll
  for (int i = 0; i < 8; ++i) { int idx = base + i; if (idx < N) off[idx] = run; run += v[i]; }
  if (t == 255) part[blockIdx.x] = s[255];
}

__global__ void scanB(int* __restrict__ part, int* __restrict__ off_last, int NB) {
  __shared__ int s[256];
  int t = threadIdx.x;
  int v = (t < NB) ? part[t] : 0;
  s[t] = v;
  __syncthreads();
  for (int ofs = 1; ofs < 256; ofs <<= 1) {
    int a = (t >= ofs) ? s[t - ofs] : 0;
    __syncthreads();
    s[t] += a;
    __syncthreads();
  }
  if (t < NB) part[t] = s[t] - v;
  if (t == NB - 1) off_last[0] = s[t];
}

__global__ void scanC(int* __restrict__ off, const int* __restrict__ part, int N) {
  int base = blockIdx.x * 2048 + threadIdx.x * 8;
  int add = part[blockIdx.x];
#pragma unroll
  for (int i = 0; i < 8; ++i) { int idx = base + i; if (idx < N) off[idx] += add; }
}

// ---- persistent XCD-owned partitioned scatter -----------------------------
// Grid MUST be exactly 2048 blocks (8 blocks/CU x 256 CU): all blocks
// resident from t=0 -> blockIdx&7 -> XCD mapping holds for the whole kernel.
// Partition p of the dest node space is written only by XCD p; its CSR
// window (~2MB) + cur counters live in that XCD's 4MB L2 and merge there.
__global__ __launch_bounds__(256) void scatter_part(
    const int* __restrict__ u_idx, const int* __restrict__ m_idx,
    const int* __restrict__ off_u, const int* __restrict__ off_m,
    int* __restrict__ cur_u, int* __restrict__ cur_m,
    int* __restrict__ csr_u, int* __restrict__ csr_m,
    int E, int nchunk, float scale_u, float scale_m) {
  int part = blockIdx.x & 7;
  int nblk = gridDim.x >> 3;  // blocks per partition
  for (int chunk = blockIdx.x >> 3; chunk < nchunk; chunk += nblk) {
    int e0 = chunk * 2048 + threadIdx.x;
#pragma unroll
    for (int i = 0; i < 8; ++i) {
      int e = e0 + i * 256;  // coalesced per i
      if (e < E) {
        int u = __builtin_nontemporal_load(&u_idx[e]);
        int m = __builtin_nontemporal_load(&m_idx[e]);
        if ((int)((float)u * scale_u) == part) {
          csr_u[off_u[u] + atomicAdd(&cur_u[u], 1)] = m;
        }
        if ((int)((float)m * scale_m) == part) {
          csr_m[off_m[m] + atomicAdd(&cur_m[m], 1)] = u;
        }
      }
    }
  }
}

// ---- weight preparation ---------------------------------------------------
// Wcat layout: [128][64] row-major; rows 0..63 aggregate weight, 64..127 root.
__global__ void mkW1(const float* __restrict__ bases1, const float* __restrict__ coeff1,
                     const float* __restrict__ root1,
                     const float* __restrict__ bases2, const float* __restrict__ coeff2,
                     float* __restrict__ Wcat1u, float* __restrict__ Wcat1m,
                     float* __restrict__ wp2, float* __restrict__ wr2) {
  int ij = blockIdx.x * 256 + threadIdx.x;  // 0..4095
  float a0 = bases1[ij], a1 = bases1[4096 + ij], a2 = bases1[8192 + ij];
  Wcat1m[ij] = coeff1[0] * a0 + coeff1[1] * a1 + coeff1[2] * a2;  // W_pays1
  Wcat1u[ij] = coeff1[3] * a0 + coeff1[4] * a1 + coeff1[5] * a2;  // W_rev1
  float r = root1[ij];
  Wcat1m[4096 + ij] = r;
  Wcat1u[4096 + ij] = r;
  float c0 = bases2[ij], c1 = bases2[4096 + ij], c2 = bases2[8192 + ij];
  wp2[ij] = coeff2[0] * c0 + coeff2[1] * c1 + coeff2[2] * c2;
  wr2[ij] = coeff2[3] * c0 + coeff2[4] * c1 + coeff2[5] * c2;
}

__global__ void mkW2(const float* __restrict__ wp2, const float* __restrict__ wr2,
                     const float* __restrict__ root2, const float* __restrict__ w_mlp1,
                     const float* __restrict__ b2, const float* __restrict__ b_mlp1,
                     float* __restrict__ Wcat2u, float* __restrict__ Wcat2m,
                     float* __restrict__ bu2, float* __restrict__ bm2) {
  int tid = blockIdx.x * 256 + threadIdx.x;  // 0..4095
  int i = tid >> 6, j = tid & 63;
  float au = 0.f, ru = 0.f, am = 0.f, rm = 0.f;
  for (int k = 0; k < 64; ++k) {
    float wa = w_mlp1[k * 64 + j];
    float wb = w_mlp1[(64 + k) * 64 + j];
    au += wr2[i * 64 + k] * wa;
    ru += root2[i * 64 + k] * wa;
    am += wp2[i * 64 + k] * wb;
    rm += root2[i * 64 + k] * wb;
  }
  Wcat2u[tid] = au; Wcat2u[4096 + tid] = ru;
  Wcat2m[tid] = am; Wcat2m[4096 + tid] = rm;
  if (i == 0) {
    float s1 = 0.f, s2 = 0.f;
    for (int k = 0; k < 64; ++k) {
      s1 += b2[k] * w_mlp1[k * 64 + j];
      s2 += b2[k] * w_mlp1[(64 + k) * 64 + j];
    }
    bu2[j] = s1;
    bm2[j] = s2 + b_mlp1[j];
  }
}

// ---- fused segment-mean + [agg|self] @ Wcat + bias (+relu) ----------------
// block = 256 = 4 waves; each wave owns 8 nodes; lane = feature.
template <int SELF_F32, int RELU>
__global__ __launch_bounds__(256) void agg_tf(
    const unsigned short* __restrict__ src,   // [Ns][64] bf16
    const void* __restrict__ selfF,           // [N][64] f32 or bf16
    const int* __restrict__ off, const int* __restrict__ csr,
    const float* __restrict__ W,              // [128][64]
    const float* __restrict__ bias,           // [64]
    unsigned short* __restrict__ out, int N) {
  __shared__ float sv[4][8][128];  // [wave][node][agg|self]
  int t = threadIdx.x, wave = t >> 6, lane = t & 63;
  int nbase = (blockIdx.x * 4 + wave) * 8;
  if (nbase >= N) return;  // whole-wave early out (no cross-wave deps)
  float b = bias[lane];
#pragma unroll
  for (int g = 0; g < 8; ++g) {
    int n = nbase + g;
    float a = 0.f, sf = 0.f;
    if (n < N) {
      int beg = off[n], end = off[n + 1], k = beg;
      for (; k + 4 <= end; k += 4) {
        int s0 = csr[k], s1 = csr[k + 1], s2 = csr[k + 2], s3 = csr[k + 3];
        float a0 = bf2f(src[(size_t)s0 * 64 + lane]);
        float a1 = bf2f(src[(size_t)s1 * 64 + lane]);
        float a2 = bf2f(src[(size_t)s2 * 64 + lane]);
        float a3 = bf2f(src[(size_t)s3 * 64 + lane]);
        a += (a0 + a1) + (a2 + a3);
      }
      for (; k < end; ++k) a += bf2f(src[(size_t)csr[k] * 64 + lane]);
      a /= fmaxf((float)(end - beg), 1.f);  // segment mean (0 if empty)
      sf = SELF_F32 ? ((const float*)selfF)[(size_t)n * 64 + lane]
                    : bf2f(((const unsigned short*)selfF)[(size_t)n * 64 + lane]);
    }
    sv[wave][g][lane] = a;
    sv[wave][g][64 + lane] = sf;
  }
  // wave-local LDS: compiler's lgkmcnt ordering suffices, no barrier
  float o[8];
#pragma unroll
  for (int g = 0; g < 8; ++g) o[g] = b;
#pragma unroll 4
  for (int k = 0; k < 128; ++k) {
    float w = W[k * 64 + lane];  // coalesced 256B, same addrs all waves -> cache broadcast
#pragma unroll
    for (int g = 0; g < 8; ++g) o[g] += sv[wave][g][k] * w;
  }
#pragma unroll
  for (int g = 0; g < 8; ++g) {
    int n = nbase + g;
    if (n < N) {
      float v = o[g];
      if (RELU) v = fmaxf(v, 0.f);
      out[(size_t)n * 64 + lane] = f2bf(v);
    }
  }
}

// ---- edge classifier, EDGE order ------------------------------------------
// logits[e] = relu(pu[u_idx[e]]+pm[m_idx[e]]) @ w_mlp2 + b_mlp2
// 16-lane subgroups: lane covers 4 features (ushort4); 4 edges per wave-iter;
// output writes are coalesced (4 consecutive float2 per wave).
__global__ __launch_bounds__(256) void edge_mlp(
    const unsigned short* __restrict__ pu, const unsigned short* __restrict__ pm,
    const int* __restrict__ u_idx, const int* __restrict__ m_idx,
    const float* __restrict__ w2, const float* __restrict__ bvec,
    float* __restrict__ out, int E) {
  int t = threadIdx.x;
  int lane = t & 63;
  int sub = lane >> 4;   // subgroup 0..3
  int fl = lane & 15;    // position in subgroup
  int f = fl * 4;        // features f..f+3
  int wid = (blockIdx.x * 256 + t) >> 6;
  int nw = (gridDim.x * 256) >> 6;
  // w2 is [64][2]; float4 j covers rows 2j,2j+1
  float4 wA = reinterpret_cast<const float4*>(w2)[2 * fl];      // rows f, f+1
  float4 wB = reinterpret_cast<const float4*>(w2)[2 * fl + 1];  // rows f+2, f+3
  float ob0 = bvec[0], ob1 = bvec[1];
  int ngrp = (E + 3) >> 2;
  for (int g = wid; g < ngrp; g += nw) {
    int e = g * 4 + sub;
    bool valid = e < E;
    int ee = valid ? e : 0;
    int u = u_idx[ee], m = m_idx[ee];
    ushort4 a4 = *reinterpret_cast<const ushort4*>(&pu[(size_t)u * 64 + f]);
    ushort4 b4 = *reinterpret_cast<const ushort4*>(&pm[(size_t)m * 64 + f]);
    float v0 = fmaxf(bf2f(a4.x) + bf2f(b4.x), 0.f);
    float v1 = fmaxf(bf2f(a4.y) + bf2f(b4.y), 0.f);
    float v2 = fmaxf(bf2f(a4.z) + bf2f(b4.z), 0.f);
    float v3 = fmaxf(bf2f(a4.w) + bf2f(b4.w), 0.f);
    float a0 = v0 * wA.x + v1 * wA.z + v2 * wB.x + v3 * wB.z;
    float a1 = v0 * wA.y + v1 * wA.w + v2 * wB.y + v3 * wB.w;
#pragma unroll
    for (int o = 8; o; o >>= 1) { a0 += __shfl_xor(a0, o); a1 += __shfl_xor(a1, o); }
    if (valid && fl == 0) {
      *reinterpret_cast<float2*>(&out[(size_t)e * 2]) = make_float2(a0 + ob0, a1 + ob1);
    }
  }
}

extern "C" void kernel_launch(void* const* d_in, const int* in_sizes, int n_in,
                              void* d_out, int out_size, void* d_ws, size_t ws_size,
                              hipStream_t stream) {
  const float* x_user  = (const float*)d_in[0];
  const float* x_merch = (const float*)d_in[1];
  const float* bases1  = (const float*)d_in[2];
  const float* coeff1  = (const float*)d_in[3];
  const float* root1   = (const float*)d_in[4];
  const float* b1      = (const float*)d_in[5];
  const float* bases2  = (const float*)d_in[6];
  const float* coeff2  = (const float*)d_in[7];
  const float* root2   = (const float*)d_in[8];
  const float* b2      = (const float*)d_in[9];
  const float* w_mlp1  = (const float*)d_in[10];
  const float* b_mlp1  = (const float*)d_in[11];
  const float* w_mlp2  = (const float*)d_in[12];
  const float* b_mlp2  = (const float*)d_in[13];
  const int*   edge_ix = (const int*)d_in[14];

  const int Nu = in_sizes[0] / 64;
  const int Nm = in_sizes[1] / 64;
  const int E  = in_sizes[14] / 2;
  const int* u_idx = edge_ix;
  const int* m_idx = edge_ix + E;

  char* p = (char*)d_ws;
  auto alloc = [&](size_t bytes) -> char* {
    char* r = p;
    p += (bytes + 255) & ~(size_t)255;
    return r;
  };
  int* off_u = (int*)alloc((size_t)(Nu + 1) * 4);
  int* off_m = (int*)alloc((size_t)(Nm + 1) * 4);
  int* zero_base = (int*)alloc((size_t)(2 * Nu + 2 * Nm) * 4);
  int* cnt_u = zero_base;
  int* cnt_m = zero_base + Nu;
  int* cur_u = zero_base + Nu + Nm;
  int* cur_m = zero_base + 2 * Nu + Nm;
  int* part_u = (int*)alloc(256 * 4);
  int* part_m = (int*)alloc(256 * 4);
  int* csr_u = (int*)alloc((size_t)E * 4);
  int* csr_m = (int*)alloc((size_t)E * 4);
  unsigned short* xb_u = (unsigned short*)alloc((size_t)Nu * 64 * 2);  // later reused as pu
  unsigned short* xb_m = (unsigned short*)alloc((size_t)Nm * 64 * 2);  // later reused as pm
  unsigned short* h_u  = (unsigned short*)alloc((size_t)Nu * 64 * 2);
  unsigned short* h_m  = (unsigned short*)alloc((size_t)Nm * 64 * 2);
  float* Wcat1u = (float*)alloc(8192 * 4);
  float* Wcat1m = (float*)alloc(8192 * 4);
  float* Wcat2u = (float*)alloc(8192 * 4);
  float* Wcat2m = (float*)alloc(8192 * 4);
  float* wp2 = (float*)alloc(4096 * 4);
  float* wr2 = (float*)alloc(4096 * 4);
  float* bu2 = (float*)alloc(64 * 4);
  float* bm2 = (float*)alloc(64 * 4);
  if ((size_t)(p - (char*)d_ws) > ws_size) return;

  hipMemsetAsync(zero_base, 0, (size_t)(2 * Nu + 2 * Nm) * 4, stream);

  int ebl = (E + 255) / 256;
  hist_kernel<<<ebl, 256, 0, stream>>>(u_idx, m_idx, cnt_u, cnt_m, E);

  int nbu = (Nu + 2047) / 2048, nbm = (Nm + 2047) / 2048;
  scanA<<<nbu, 256, 0, stream>>>(cnt_u, off_u, part_u, Nu);
  scanB<<<1, 256, 0, stream>>>(part_u, off_u + Nu, nbu);
  scanC<<<nbu, 256, 0, stream>>>(off_u, part_u, Nu);
  scanA<<<nbm, 256, 0, stream>>>(cnt_m, off_m, part_m, Nm);
  scanB<<<1, 256, 0, stream>>>(part_m, off_m + Nm, nbm);
  scanC<<<nbm, 256, 0, stream>>>(off_m, part_m, Nm);

  // persistent XCD-owned scatter: EXACTLY 2048 blocks (8/CU x 256 CU)
  int nchunk = (E + 2047) / 2048;
  float scale_u = 8.0f / (float)Nu * (1.0f - 1e-7f);  // maps u -> 0..7
  float scale_m = 8.0f / (float)Nm * (1.0f - 1e-7f);
  scatter_part<<<2048, 256, 0, stream>>>(u_idx, m_idx, off_u, off_m,
                                         cur_u, cur_m, csr_u, csr_m,
                                         E, nchunk, scale_u, scale_m);

  tobf16<<<1024, 256, 0, stream>>>(x_user, xb_u, Nu * 16);
  tobf16<<<256, 256, 0, stream>>>(x_merch, xb_m, Nm * 16);

  mkW1<<<16, 256, 0, stream>>>(bases1, coeff1, root1, bases2, coeff2,
                               Wcat1u, Wcat1m, wp2, wr2);
  mkW2<<<16, 256, 0, stream>>>(wp2, wr2, root2, w_mlp1, b2, b_mlp1,
                               Wcat2u, Wcat2m, bu2, bm2);

  int gbu = (Nu + 31) / 32, gbm = (Nm + 31) / 32;
  // layer 1 (relu): self from original f32 arrays
  agg_tf<1, 1><<<gbu, 256, 0, stream>>>(xb_m, x_user, off_u, csr_u, Wcat1u, b1, h_u, Nu);
  agg_tf<1, 1><<<gbm, 256, 0, stream>>>(xb_u, x_merch, off_m, csr_m, Wcat1m, b1, h_m, Nm);
  // layer 2 fused with edge-MLP left matrix; outputs reuse xb buffers
  unsigned short* pm_buf = xb_m;  // xb_m last read by layer-1 user agg (done)
  unsigned short* pu_buf = xb_u;  // xb_u last read by layer-1 merch agg (done)
  agg_tf<0, 0><<<gbm, 256, 0, stream>>>(h_u, h_m, off_m, csr_m, Wcat2m, bm2, pm_buf, Nm);
  agg_tf<0, 0><<<gbu, 256, 0, stream>>>(h_m, h_u, off_u, csr_u, Wcat2u, bu2, pu_buf, Nu);

  edge_mlp<<<2048, 256, 0, stream>>>(pu_buf, pm_buf, u_idx, m_idx,
                                     w_mlp2, b_mlp2, (float*)d_out, E);
}

// Round 6
// 844.168 us; speedup vs baseline: 1.3982x; 1.3187x over previous
//
#include <hip/hip_runtime.h>

// ---------------------------------------------------------------------------
// Hetero-SAGE edge classifier.
//  Round-6: atomic-free CSR build via 2-level MSD bucket sort.
//  R5 post-mortem: ~140MB of the scatter's WRITE_SIZE was 4M device-scope
//  atomicAdds (uncacheable RMW through non-coherent per-XCD L2s) + ~4.5x
//  line amplification on scattered 4B stores. Sort-based build uses only
//  LDS atomics and contiguous-run writes:
//   K1 sort_hist: per-chunk LDS hist of high digit (u>>10 / m>>8)
//   scanA/B/C over [bin][blk] hist -> per-(bin,chunk) contiguous cursors
//   K3 sort_scatter1: partition edges into 196 buckets (contiguous runs)
//   K4 sort_bucket: block-per-bucket low-digit counting sort; writes off[]
//      directly from cursor bases (no hist/scan/mkoff over nodes) and
//      values-only CSR (4B/entry).
//  Rest as R5: bf16 tables, fused agg+transform, layer-2 weights pre-fused
//  with edge-MLP, edge-order edge_mlp.
// ---------------------------------------------------------------------------

__device__ inline unsigned short f2bf(float f) {
  unsigned u = __float_as_uint(f);
  u += 0x7FFF + ((u >> 16) & 1);  // round-to-nearest-even
  return (unsigned short)(u >> 16);
}
__device__ inline float bf2f(unsigned short h) {
  return __uint_as_float(((unsigned)h) << 16);
}

__global__ void tobf16(const float* __restrict__ in, unsigned short* __restrict__ out, int n4) {
  int i = blockIdx.x * 256 + threadIdx.x;
  int stride = gridDim.x * 256;
  for (int j = i; j < n4; j += stride) {
    float4 v = reinterpret_cast<const float4*>(in)[j];
    ushort4 o;
    o.x = f2bf(v.x); o.y = f2bf(v.y); o.z = f2bf(v.z); o.w = f2bf(v.w);
    reinterpret_cast<ushort4*>(out)[j] = o;
  }
}

// ---- 3-phase exclusive scan (chunk = 2048 = 256 threads * 8 items) --------
__global__ void scanA(const int* __restrict__ cnt, int* __restrict__ off,
                      int* __restrict__ part, int N) {
  __shared__ int s[256];
  int t = threadIdx.x;
  int base = blockIdx.x * 2048 + t * 8;
  int v[8]; int sum = 0;
#pragma unroll
  for (int i = 0; i < 8; ++i) { int idx = base + i; v[i] = (idx < N) ? cnt[idx] : 0; sum += v[i]; }
  s[t] = sum;
  __syncthreads();
  for (int ofs = 1; ofs < 256; ofs <<= 1) {
    int a = (t >= ofs) ? s[t - ofs] : 0;
    __syncthreads();
    s[t] += a;
    __syncthreads();
  }
  int run = s[t] - sum;
#pragma unroll
  for (int i = 0; i < 8; ++i) { int idx = base + i; if (idx < N) off[idx] = run; run += v[i]; }
  if (t == 255) part[blockIdx.x] = s[255];
}

__global__ void scanB(int* __restrict__ part, int* __restrict__ off_last, int NB) {
  __shared__ int s[256];
  int t = threadIdx.x;
  int v = (t < NB) ? part[t] : 0;
  s[t] = v;
  __syncthreads();
  for (int ofs = 1; ofs < 256; ofs <<= 1) {
    int a = (t >= ofs) ? s[t - ofs] : 0;
    __syncthreads();
    s[t] += a;
    __syncthreads();
  }
  if (t < NB) part[t] = s[t] - v;
  if (t == NB - 1) off_last[0] = s[t];
}

__global__ void scanC(int* __restrict__ off, const int* __restrict__ part, int N) {
  int base = blockIdx.x * 2048 + threadIdx.x * 8;
  int add = part[blockIdx.x];
#pragma unroll
  for (int i = 0; i < 8; ++i) { int idx = base + i; if (idx < N) off[idx] += add; }
}

// ---- K1: per-chunk dual histogram of high digits (LDS atomics only) -------
__global__ __launch_bounds__(256) void sort_hist(
    const int* __restrict__ u_idx, const int* __restrict__ m_idx,
    int* __restrict__ hist_u, int* __restrict__ hist_m, int E, int nblk) {
  __shared__ int hu[256], hm[256];
  int t = threadIdx.x, blk = blockIdx.x;
  hu[t] = 0; hm[t] = 0;
  __syncthreads();
  int e0 = blk * 2048 + t;
#pragma unroll
  for (int i = 0; i < 8; ++i) {
    int e = e0 + i * 256;
    if (e < E) {
      atomicAdd(&hu[u_idx[e] >> 10], 1);
      atomicAdd(&hm[m_idx[e] >> 8], 1);
    }
  }
  __syncthreads();
  hist_u[t * nblk + blk] = hu[t];  // [bin][blk] layout for bucket-contiguous scan
  hist_m[t * nblk + blk] = hm[t];
}

// ---- K3: partition edges into high-digit buckets --------------------------
// cursors = scanned hist; each (block,bin) writes a contiguous ~80B run.
__global__ __launch_bounds__(256) void sort_scatter1(
    const int* __restrict__ u_idx, const int* __restrict__ m_idx,
    const int* __restrict__ base_u, const int* __restrict__ base_m,
    int2* __restrict__ stage_u, int2* __restrict__ stage_m, int E, int nblk) {
  __shared__ int cu[256], cm[256];
  int t = threadIdx.x, blk = blockIdx.x;
  cu[t] = base_u[t * nblk + blk];
  cm[t] = base_m[t * nblk + blk];
  __syncthreads();
  int e0 = blk * 2048 + t;
#pragma unroll
  for (int i = 0; i < 8; ++i) {
    int e = e0 + i * 256;
    if (e < E) {
      int u = u_idx[e], m = m_idx[e];
      int pu = atomicAdd(&cu[u >> 10], 1);
      stage_u[pu] = make_int2(u, m);
      int pm = atomicAdd(&cm[m >> 8], 1);
      stage_m[pm] = make_int2(m, u);
    }
  }
}

// ---- K4: block-per-bucket low-digit counting sort -------------------------
// Also writes off[] for every node in the bucket (cursor base == segment
// start; empty keys get the correct position; node==N gets E from the last
// non-empty bucket). Output CSR is values-only.
template <int LOWBITS>
__global__ __launch_bounds__(256) void sort_bucket(
    const int2* __restrict__ stage, const int* __restrict__ hs,
    int* __restrict__ vals_out, int* __restrict__ off,
    int E, int N, int nblk) {
  constexpr int NBIN = 1 << LOWBITS;
  constexpr int R = NBIN / 256;
  __shared__ int h[NBIN];
  __shared__ int s[256];
  int t = threadIdx.x, b = blockIdx.x;
  int seg0 = hs[b * nblk];
  int seg1 = (b == 255) ? E : hs[(b + 1) * nblk];
#pragma unroll
  for (int r = 0; r < R; ++r) h[t * R + r] = 0;
  __syncthreads();
  for (int i = seg0 + t; i < seg1; i += 256)
    atomicAdd(&h[stage[i].x & (NBIN - 1)], 1);
  __syncthreads();
  // exclusive scan over NBIN bins; thread t owns bins [t*R, t*R+R)
  int vals[R]; int loc = 0;
#pragma unroll
  for (int r = 0; r < R; ++r) { vals[r] = h[t * R + r]; loc += vals[r]; }
  s[t] = loc;
  __syncthreads();
  for (int ofs = 1; ofs < 256; ofs <<= 1) {
    int a = (t >= ofs) ? s[t - ofs] : 0;
    __syncthreads();
    s[t] += a;
    __syncthreads();
  }
  int run = seg0 + s[t] - loc;
#pragma unroll
  for (int r = 0; r < R; ++r) {
    int bin = t * R + r;
    h[bin] = run;
    int node = (b << LOWBITS) + bin;
    if (node <= N) off[node] = run;   // segment start; node==N -> E
    run += vals[r];
  }
  __syncthreads();
  for (int i = seg0 + t; i < seg1; i += 256) {
    int2 v = stage[i];
    int pos = atomicAdd(&h[v.x & (NBIN - 1)], 1);
    vals_out[pos] = v.y;
  }
}

// ---- weight preparation ---------------------------------------------------
// Wcat layout: [128][64] row-major; rows 0..63 aggregate weight, 64..127 root.
__global__ void mkW1(const float* __restrict__ bases1, const float* __restrict__ coeff1,
                     const float* __restrict__ root1,
                     const float* __restrict__ bases2, const float* __restrict__ coeff2,
                     float* __restrict__ Wcat1u, float* __restrict__ Wcat1m,
                     float* __restrict__ wp2, float* __restrict__ wr2) {
  int ij = blockIdx.x * 256 + threadIdx.x;  // 0..4095
  float a0 = bases1[ij], a1 = bases1[4096 + ij], a2 = bases1[8192 + ij];
  Wcat1m[ij] = coeff1[0] * a0 + coeff1[1] * a1 + coeff1[2] * a2;  // W_pays1
  Wcat1u[ij] = coeff1[3] * a0 + coeff1[4] * a1 + coeff1[5] * a2;  // W_rev1
  float r = root1[ij];
  Wcat1m[4096 + ij] = r;
  Wcat1u[4096 + ij] = r;
  float c0 = bases2[ij], c1 = bases2[4096 + ij], c2 = bases2[8192 + ij];
  wp2[ij] = coeff2[0] * c0 + coeff2[1] * c1 + coeff2[2] * c2;
  wr2[ij] = coeff2[3] * c0 + coeff2[4] * c1 + coeff2[5] * c2;
}

__global__ void mkW2(const float* __restrict__ wp2, const float* __restrict__ wr2,
                     const float* __restrict__ root2, const float* __restrict__ w_mlp1,
                     const float* __restrict__ b2, const float* __restrict__ b_mlp1,
                     float* __restrict__ Wcat2u, float* __restrict__ Wcat2m,
                     float* __restrict__ bu2, float* __restrict__ bm2) {
  int tid = blockIdx.x * 256 + threadIdx.x;  // 0..4095
  int i = tid >> 6, j = tid & 63;
  float au = 0.f, ru = 0.f, am = 0.f, rm = 0.f;
  for (int k = 0; k < 64; ++k) {
    float wa = w_mlp1[k * 64 + j];
    float wb = w_mlp1[(64 + k) * 64 + j];
    au += wr2[i * 64 + k] * wa;
    ru += root2[i * 64 + k] * wa;
    am += wp2[i * 64 + k] * wb;
    rm += root2[i * 64 + k] * wb;
  }
  Wcat2u[tid] = au; Wcat2u[4096 + tid] = ru;
  Wcat2m[tid] = am; Wcat2m[4096 + tid] = rm;
  if (i == 0) {
    float s1 = 0.f, s2 = 0.f;
    for (int k = 0; k < 64; ++k) {
      s1 += b2[k] * w_mlp1[k * 64 + j];
      s2 += b2[k] * w_mlp1[(64 + k) * 64 + j];
    }
    bu2[j] = s1;
    bm2[j] = s2 + b_mlp1[j];
  }
}

// ---- fused segment-mean + [agg|self] @ Wcat + bias (+relu) ----------------
// block = 256 = 4 waves; each wave owns 8 nodes; lane = feature.
template <int SELF_F32, int RELU>
__global__ __launch_bounds__(256) void agg_tf(
    const unsigned short* __restrict__ src,   // [Ns][64] bf16
    const void* __restrict__ selfF,           // [N][64] f32 or bf16
    const int* __restrict__ off, const int* __restrict__ csr,
    const float* __restrict__ W,              // [128][64]
    const float* __restrict__ bias,           // [64]
    unsigned short* __restrict__ out, int N) {
  __shared__ float sv[4][8][128];  // [wave][node][agg|self]
  int t = threadIdx.x, wave = t >> 6, lane = t & 63;
  int nbase = (blockIdx.x * 4 + wave) * 8;
  if (nbase >= N) return;  // whole-wave early out (no cross-wave deps)
  float b = bias[lane];
#pragma unroll
  for (int g = 0; g < 8; ++g) {
    int n = nbase + g;
    float a = 0.f, sf = 0.f;
    if (n < N) {
      int beg = off[n], end = off[n + 1], k = beg;
      for (; k + 4 <= end; k += 4) {
        int s0 = csr[k], s1 = csr[k + 1], s2 = csr[k + 2], s3 = csr[k + 3];
        float a0 = bf2f(src[(size_t)s0 * 64 + lane]);
        float a1 = bf2f(src[(size_t)s1 * 64 + lane]);
        float a2 = bf2f(src[(size_t)s2 * 64 + lane]);
        float a3 = bf2f(src[(size_t)s3 * 64 + lane]);
        a += (a0 + a1) + (a2 + a3);
      }
      for (; k < end; ++k) a += bf2f(src[(size_t)csr[k] * 64 + lane]);
      a /= fmaxf((float)(end - beg), 1.f);  // segment mean (0 if empty)
      sf = SELF_F32 ? ((const float*)selfF)[(size_t)n * 64 + lane]
                    : bf2f(((const unsigned short*)selfF)[(size_t)n * 64 + lane]);
    }
    sv[wave][g][lane] = a;
    sv[wave][g][64 + lane] = sf;
  }
  // wave-local LDS: compiler's lgkmcnt ordering suffices, no barrier
  float o[8];
#pragma unroll
  for (int g = 0; g < 8; ++g) o[g] = b;
#pragma unroll 4
  for (int k = 0; k < 128; ++k) {
    float w = W[k * 64 + lane];  // coalesced 256B, same addrs all waves -> cache broadcast
#pragma unroll
    for (int g = 0; g < 8; ++g) o[g] += sv[wave][g][k] * w;
  }
#pragma unroll
  for (int g = 0; g < 8; ++g) {
    int n = nbase + g;
    if (n < N) {
      float v = o[g];
      if (RELU) v = fmaxf(v, 0.f);
      out[(size_t)n * 64 + lane] = f2bf(v);
    }
  }
}

// ---- edge classifier, EDGE order ------------------------------------------
// logits[e] = relu(pu[u_idx[e]]+pm[m_idx[e]]) @ w_mlp2 + b_mlp2
__global__ __launch_bounds__(256) void edge_mlp(
    const unsigned short* __restrict__ pu, const unsigned short* __restrict__ pm,
    const int* __restrict__ u_idx, const int* __restrict__ m_idx,
    const float* __restrict__ w2, const float* __restrict__ bvec,
    float* __restrict__ out, int E) {
  int t = threadIdx.x;
  int lane = t & 63;
  int sub = lane >> 4;   // subgroup 0..3
  int fl = lane & 15;    // position in subgroup
  int f = fl * 4;        // features f..f+3
  int wid = (blockIdx.x * 256 + t) >> 6;
  int nw = (gridDim.x * 256) >> 6;
  float4 wA = reinterpret_cast<const float4*>(w2)[2 * fl];      // rows f, f+1
  float4 wB = reinterpret_cast<const float4*>(w2)[2 * fl + 1];  // rows f+2, f+3
  float ob0 = bvec[0], ob1 = bvec[1];
  int ngrp = (E + 3) >> 2;
  for (int g = wid; g < ngrp; g += nw) {
    int e = g * 4 + sub;
    bool valid = e < E;
    int ee = valid ? e : 0;
    int u = u_idx[ee], m = m_idx[ee];
    ushort4 a4 = *reinterpret_cast<const ushort4*>(&pu[(size_t)u * 64 + f]);
    ushort4 b4 = *reinterpret_cast<const ushort4*>(&pm[(size_t)m * 64 + f]);
    float v0 = fmaxf(bf2f(a4.x) + bf2f(b4.x), 0.f);
    float v1 = fmaxf(bf2f(a4.y) + bf2f(b4.y), 0.f);
    float v2 = fmaxf(bf2f(a4.z) + bf2f(b4.z), 0.f);
    float v3 = fmaxf(bf2f(a4.w) + bf2f(b4.w), 0.f);
    float a0 = v0 * wA.x + v1 * wA.z + v2 * wB.x + v3 * wB.z;
    float a1 = v0 * wA.y + v1 * wA.w + v2 * wB.y + v3 * wB.w;
#pragma unroll
    for (int o = 8; o; o >>= 1) { a0 += __shfl_xor(a0, o); a1 += __shfl_xor(a1, o); }
    if (valid && fl == 0) {
      *reinterpret_cast<float2*>(&out[(size_t)e * 2]) = make_float2(a0 + ob0, a1 + ob1);
    }
  }
}

extern "C" void kernel_launch(void* const* d_in, const int* in_sizes, int n_in,
                              void* d_out, int out_size, void* d_ws, size_t ws_size,
                              hipStream_t stream) {
  const float* x_user  = (const float*)d_in[0];
  const float* x_merch = (const float*)d_in[1];
  const float* bases1  = (const float*)d_in[2];
  const float* coeff1  = (const float*)d_in[3];
  const float* root1   = (const float*)d_in[4];
  const float* b1      = (const float*)d_in[5];
  const float* bases2  = (const float*)d_in[6];
  const float* coeff2  = (const float*)d_in[7];
  const float* root2   = (const float*)d_in[8];
  const float* b2      = (const float*)d_in[9];
  const float* w_mlp1  = (const float*)d_in[10];
  const float* b_mlp1  = (const float*)d_in[11];
  const float* w_mlp2  = (const float*)d_in[12];
  const float* b_mlp2  = (const float*)d_in[13];
  const int*   edge_ix = (const int*)d_in[14];

  const int Nu = in_sizes[0] / 64;
  const int Nm = in_sizes[1] / 64;
  const int E  = in_sizes[14] / 2;
  const int* u_idx = edge_ix;
  const int* m_idx = edge_ix + E;

  char* p = (char*)d_ws;
  auto alloc = [&](size_t bytes) -> char* {
    char* r = p;
    p += (bytes + 255) & ~(size_t)255;
    return r;
  };
  int* off_u = (int*)alloc((size_t)(Nu + 1) * 4);
  int* off_m = (int*)alloc((size_t)(Nm + 1) * 4);
  int* part  = (int*)alloc(512 * 4);
  int* csr_u = (int*)alloc((size_t)E * 4);   // merchants grouped by user
  int* csr_m = (int*)alloc((size_t)E * 4);   // users grouped by merchant
  unsigned short* xb_u = (unsigned short*)alloc((size_t)Nu * 64 * 2);  // also: stage_m alias; later pu
  unsigned short* xb_m = (unsigned short*)alloc((size_t)Nm * 64 * 2);  // later pm
  unsigned short* h_u  = (unsigned short*)alloc((size_t)Nu * 64 * 2);  // also: stage_u alias
  unsigned short* h_m  = (unsigned short*)alloc((size_t)Nm * 64 * 2);  // also: hist alias
  float* Wcat1u = (float*)alloc(8192 * 4);
  float* Wcat1m = (float*)alloc(8192 * 4);
  float* Wcat2u = (float*)alloc(8192 * 4);
  float* Wcat2m = (float*)alloc(8192 * 4);
  float* wp2 = (float*)alloc(4096 * 4);
  float* wr2 = (float*)alloc(4096 * 4);
  float* bu2 = (float*)alloc(64 * 4);
  float* bm2 = (float*)alloc(64 * 4);
  if ((size_t)(p - (char*)d_ws) > ws_size) return;

  const int nblk = (E + 2047) / 2048;   // 977
  const int nhist = 256 * nblk;         // 250112
  // aliases (lifetimes verified: sorts complete before tobf16 / agg writes)
  int*  hist_u  = (int*)h_m;            // dead before h_m written (layer 1)
  int*  hist_m  = hist_u + nhist;       // 2*nhist ints = 2MB << 6.4MB
  int2* stage_u = (int2*)h_u;           // dead before h_u written (layer 1)
  int2* stage_m = (int2*)xb_u;          // dead before xb_u written (tobf16)

  // ---- CSR build: 2-level bucket sort, zero global atomics ----
  sort_hist<<<nblk, 256, 0, stream>>>(u_idx, m_idx, hist_u, hist_m, E, nblk);
  int sb = (nhist + 2047) / 2048;       // 123
  scanA<<<sb, 256, 0, stream>>>(hist_u, hist_u, part, nhist);
  scanB<<<1, 256, 0, stream>>>(part, part + 400, sb);
  scanC<<<sb, 256, 0, stream>>>(hist_u, part, nhist);
  scanA<<<sb, 256, 0, stream>>>(hist_m, hist_m, part, nhist);
  scanB<<<1, 256, 0, stream>>>(part, part + 400, sb);
  scanC<<<sb, 256, 0, stream>>>(hist_m, part, nhist);
  sort_scatter1<<<nblk, 256, 0, stream>>>(u_idx, m_idx, hist_u, hist_m,
                                          stage_u, stage_m, E, nblk);
  sort_bucket<10><<<256, 256, 0, stream>>>(stage_u, hist_u, csr_u, off_u, E, Nu, nblk);
  sort_bucket<8><<<256, 256, 0, stream>>>(stage_m, hist_m, csr_m, off_m, E, Nm, nblk);

  // ---- feature tables & weights ----
  tobf16<<<1024, 256, 0, stream>>>(x_user, xb_u, Nu * 16);
  tobf16<<<256, 256, 0, stream>>>(x_merch, xb_m, Nm * 16);
  mkW1<<<16, 256, 0, stream>>>(bases1, coeff1, root1, bases2, coeff2,
                               Wcat1u, Wcat1m, wp2, wr2);
  mkW2<<<16, 256, 0, stream>>>(wp2, wr2, root2, w_mlp1, b2, b_mlp1,
                               Wcat2u, Wcat2m, bu2, bm2);

  int gbu = (Nu + 31) / 32, gbm = (Nm + 31) / 32;
  // layer 1 (relu): self from original f32 arrays
  agg_tf<1, 1><<<gbu, 256, 0, stream>>>(xb_m, x_user, off_u, csr_u, Wcat1u, b1, h_u, Nu);
  agg_tf<1, 1><<<gbm, 256, 0, stream>>>(xb_u, x_merch, off_m, csr_m, Wcat1m, b1, h_m, Nm);
  // layer 2 fused with edge-MLP left matrix; outputs reuse xb buffers
  unsigned short* pm_buf = xb_m;
  unsigned short* pu_buf = xb_u;
  agg_tf<0, 0><<<gbm, 256, 0, stream>>>(h_u, h_m, off_m, csr_m, Wcat2m, bm2, pm_buf, Nm);
  agg_tf<0, 0><<<gbu, 256, 0, stream>>>(h_m, h_u, off_u, csr_u, Wcat2u, bu2, pu_buf, Nu);

  edge_mlp<<<2048, 256, 0, stream>>>(pu_buf, pm_buf, u_idx, m_idx,
                                     w_mlp2, b_mlp2, (float*)d_out, E);
}

// Round 7
// 700.249 us; speedup vs baseline: 1.6855x; 1.2055x over previous
//
#include <hip/hip_runtime.h>

// ---------------------------------------------------------------------------
// Hetero-SAGE edge classifier.
//  Round-7: MFMA transform in agg_tf. R6 profile: agg_tf dominates (183us,
//  VALUBusy 52%, MfmaUtil 0) — the [128]x[64] per-node transform costs ~17
//  VALU inst per k-step (8 scalar ds_read broadcasts + 8 FMA). Replace with
//  mfma_f32_16x16x32_bf16: wave owns 16 nodes, A-tile [16][128] bf16 in LDS
//  (XOR-swizzled per G4 — unswizzled b128 frag reads are 16-way conflicts),
//  W pre-packed to B-fragment lane layout, bias in accumulator.
//  CSR build (bucket sort) / edge_mlp / weight prep unchanged from R6.
// ---------------------------------------------------------------------------

typedef __attribute__((ext_vector_type(8))) short short8;
typedef __attribute__((ext_vector_type(4))) float f32x4;

__device__ inline unsigned short f2bf(float f) {
  unsigned u = __float_as_uint(f);
  u += 0x7FFF + ((u >> 16) & 1);  // round-to-nearest-even
  return (unsigned short)(u >> 16);
}
__device__ inline float bf2f(unsigned short h) {
  return __uint_as_float(((unsigned)h) << 16);
}

__global__ void tobf16(const float* __restrict__ in, unsigned short* __restrict__ out, int n4) {
  int i = blockIdx.x * 256 + threadIdx.x;
  int stride = gridDim.x * 256;
  for (int j = i; j < n4; j += stride) {
    float4 v = reinterpret_cast<const float4*>(in)[j];
    ushort4 o;
    o.x = f2bf(v.x); o.y = f2bf(v.y); o.z = f2bf(v.z); o.w = f2bf(v.w);
    reinterpret_cast<ushort4*>(out)[j] = o;
  }
}

// ---- 3-phase exclusive scan (chunk = 2048 = 256 threads * 8 items) --------
__global__ void scanA(const int* __restrict__ cnt, int* __restrict__ off,
                      int* __restrict__ part, int N) {
  __shared__ int s[256];
  int t = threadIdx.x;
  int base = blockIdx.x * 2048 + t * 8;
  int v[8]; int sum = 0;
#pragma unroll
  for (int i = 0; i < 8; ++i) { int idx = base + i; v[i] = (idx < N) ? cnt[idx] : 0; sum += v[i]; }
  s[t] = sum;
  __syncthreads();
  for (int ofs = 1; ofs < 256; ofs <<= 1) {
    int a = (t >= ofs) ? s[t - ofs] : 0;
    __syncthreads();
    s[t] += a;
    __syncthreads();
  }
  int run = s[t] - sum;
#pragma unroll
  for (int i = 0; i < 8; ++i) { int idx = base + i; if (idx < N) off[idx] = run; run += v[i]; }
  if (t == 255) part[blockIdx.x] = s[255];
}

__global__ void scanB(int* __restrict__ part, int* __restrict__ off_last, int NB) {
  __shared__ int s[256];
  int t = threadIdx.x;
  int v = (t < NB) ? part[t] : 0;
  s[t] = v;
  __syncthreads();
  for (int ofs = 1; ofs < 256; ofs <<= 1) {
    int a = (t >= ofs) ? s[t - ofs] : 0;
    __syncthreads();
    s[t] += a;
    __syncthreads();
  }
  if (t < NB) part[t] = s[t] - v;
  if (t == NB - 1) off_last[0] = s[t];
}

__global__ void scanC(int* __restrict__ off, const int* __restrict__ part, int N) {
  int base = blockIdx.x * 2048 + threadIdx.x * 8;
  int add = part[blockIdx.x];
#pragma unroll
  for (int i = 0; i < 8; ++i) { int idx = base + i; if (idx < N) off[idx] += add; }
}

// ---- K1: per-chunk dual histogram of high digits (LDS atomics only) -------
__global__ __launch_bounds__(256) void sort_hist(
    const int* __restrict__ u_idx, const int* __restrict__ m_idx,
    int* __restrict__ hist_u, int* __restrict__ hist_m, int E, int nblk) {
  __shared__ int hu[256], hm[256];
  int t = threadIdx.x, blk = blockIdx.x;
  hu[t] = 0; hm[t] = 0;
  __syncthreads();
  int e0 = blk * 2048 + t;
#pragma unroll
  for (int i = 0; i < 8; ++i) {
    int e = e0 + i * 256;
    if (e < E) {
      atomicAdd(&hu[u_idx[e] >> 10], 1);
      atomicAdd(&hm[m_idx[e] >> 8], 1);
    }
  }
  __syncthreads();
  hist_u[t * nblk + blk] = hu[t];  // [bin][blk] layout for bucket-contiguous scan
  hist_m[t * nblk + blk] = hm[t];
}

// ---- K3: partition edges into high-digit buckets --------------------------
__global__ __launch_bounds__(256) void sort_scatter1(
    const int* __restrict__ u_idx, const int* __restrict__ m_idx,
    const int* __restrict__ base_u, const int* __restrict__ base_m,
    int2* __restrict__ stage_u, int2* __restrict__ stage_m, int E, int nblk) {
  __shared__ int cu[256], cm[256];
  int t = threadIdx.x, blk = blockIdx.x;
  cu[t] = base_u[t * nblk + blk];
  cm[t] = base_m[t * nblk + blk];
  __syncthreads();
  int e0 = blk * 2048 + t;
#pragma unroll
  for (int i = 0; i < 8; ++i) {
    int e = e0 + i * 256;
    if (e < E) {
      int u = u_idx[e], m = m_idx[e];
      int pu = atomicAdd(&cu[u >> 10], 1);
      stage_u[pu] = make_int2(u, m);
      int pm = atomicAdd(&cm[m >> 8], 1);
      stage_m[pm] = make_int2(m, u);
    }
  }
}

// ---- K4: block-per-bucket low-digit counting sort -------------------------
template <int LOWBITS>
__global__ __launch_bounds__(256) void sort_bucket(
    const int2* __restrict__ stage, const int* __restrict__ hs,
    int* __restrict__ vals_out, int* __restrict__ off,
    int E, int N, int nblk) {
  constexpr int NBIN = 1 << LOWBITS;
  constexpr int R = NBIN / 256;
  __shared__ int h[NBIN];
  __shared__ int s[256];
  int t = threadIdx.x, b = blockIdx.x;
  int seg0 = hs[b * nblk];
  int seg1 = (b == 255) ? E : hs[(b + 1) * nblk];
#pragma unroll
  for (int r = 0; r < R; ++r) h[t * R + r] = 0;
  __syncthreads();
  for (int i = seg0 + t; i < seg1; i += 256)
    atomicAdd(&h[stage[i].x & (NBIN - 1)], 1);
  __syncthreads();
  int vals[R]; int loc = 0;
#pragma unroll
  for (int r = 0; r < R; ++r) { vals[r] = h[t * R + r]; loc += vals[r]; }
  s[t] = loc;
  __syncthreads();
  for (int ofs = 1; ofs < 256; ofs <<= 1) {
    int a = (t >= ofs) ? s[t - ofs] : 0;
    __syncthreads();
    s[t] += a;
    __syncthreads();
  }
  int run = seg0 + s[t] - loc;
#pragma unroll
  for (int r = 0; r < R; ++r) {
    int bin = t * R + r;
    h[bin] = run;
    int node = (b << LOWBITS) + bin;
    if (node <= N) off[node] = run;   // segment start; node==N -> E
    run += vals[r];
  }
  __syncthreads();
  for (int i = seg0 + t; i < seg1; i += 256) {
    int2 v = stage[i];
    int pos = atomicAdd(&h[v.x & (NBIN - 1)], 1);
    vals_out[pos] = v.y;
  }
}

// ---- weight preparation ---------------------------------------------------
// Wcat layout: [128][64] row-major; rows 0..63 aggregate weight, 64..127 root.
__global__ void mkW1(const float* __restrict__ bases1, const float* __restrict__ coeff1,
                     const float* __restrict__ root1,
                     const float* __restrict__ bases2, const float* __restrict__ coeff2,
                     float* __restrict__ Wcat1u, float* __restrict__ Wcat1m,
                     float* __restrict__ wp2, float* __restrict__ wr2) {
  int ij = blockIdx.x * 256 + threadIdx.x;  // 0..4095
  float a0 = bases1[ij], a1 = bases1[4096 + ij], a2 = bases1[8192 + ij];
  Wcat1m[ij] = coeff1[0] * a0 + coeff1[1] * a1 + coeff1[2] * a2;  // W_pays1
  Wcat1u[ij] = coeff1[3] * a0 + coeff1[4] * a1 + coeff1[5] * a2;  // W_rev1
  float r = root1[ij];
  Wcat1m[4096 + ij] = r;
  Wcat1u[4096 + ij] = r;
  float c0 = bases2[ij], c1 = bases2[4096 + ij], c2 = bases2[8192 + ij];
  wp2[ij] = coeff2[0] * c0 + coeff2[1] * c1 + coeff2[2] * c2;
  wr2[ij] = coeff2[3] * c0 + coeff2[4] * c1 + coeff2[5] * c2;
}

__global__ void mkW2(const float* __restrict__ wp2, const float* __restrict__ wr2,
                     const float* __restrict__ root2, const float* __restrict__ w_mlp1,
                     const float* __restrict__ b2, const float* __restrict__ b_mlp1,
                     float* __restrict__ Wcat2u, float* __restrict__ Wcat2m,
                     float* __restrict__ bu2, float* __restrict__ bm2) {
  int tid = blockIdx.x * 256 + threadIdx.x;  // 0..4095
  int i = tid >> 6, j = tid & 63;
  float au = 0.f, ru = 0.f, am = 0.f, rm = 0.f;
  for (int k = 0; k < 64; ++k) {
    float wa = w_mlp1[k * 64 + j];
    float wb = w_mlp1[(64 + k) * 64 + j];
    au += wr2[i * 64 + k] * wa;
    ru += root2[i * 64 + k] * wa;
    am += wp2[i * 64 + k] * wb;
    rm += root2[i * 64 + k] * wb;
  }
  Wcat2u[tid] = au; Wcat2u[4096 + tid] = ru;
  Wcat2m[tid] = am; Wcat2m[4096 + tid] = rm;
  if (i == 0) {
    float s1 = 0.f, s2 = 0.f;
    for (int k = 0; k < 64; ++k) {
      s1 += b2[k] * w_mlp1[k * 64 + j];
      s2 += b2[k] * w_mlp1[(64 + k) * 64 + j];
    }
    bu2[j] = s1;
    bm2[j] = s2 + b_mlp1[j];
  }
}

// ---- pack Wcat [128][64] f32 into MFMA B-fragment layout, bf16 ------------
// Wp[tid]: frag = tid>>9 (nt*4+ks), lane = (tid>>3)&63, i = tid&7
// value = Wcat[ks*32 + (lane>>4)*8 + i][nt*16 + (lane&15)]
__global__ void packW4(const float* __restrict__ s0, const float* __restrict__ s1,
                       const float* __restrict__ s2, const float* __restrict__ s3,
                       unsigned short* __restrict__ d0, unsigned short* __restrict__ d1,
                       unsigned short* __restrict__ d2, unsigned short* __restrict__ d3) {
  int gid = blockIdx.x * 256 + threadIdx.x;   // 0..32767
  int mat = gid >> 13;                        // 0..3
  int tid = gid & 8191;
  int frag = tid >> 9;
  int nt = frag >> 2, ks = frag & 3;
  int lane = (tid >> 3) & 63;
  int i = tid & 7;
  int k = ks * 32 + (lane >> 4) * 8 + i;
  int col = nt * 16 + (lane & 15);
  const float* s = (mat == 0) ? s0 : (mat == 1) ? s1 : (mat == 2) ? s2 : s3;
  unsigned short* d = (mat == 0) ? d0 : (mat == 1) ? d1 : (mat == 2) ? d2 : d3;
  d[tid] = f2bf(s[k * 64 + col]);
}

// ---- fused segment-mean + MFMA transform + bias (+relu) -------------------
// block = 256 = 4 waves; wave owns 16 nodes; gather: lane = src feature.
// A-tile [16][128] bf16 in LDS, XOR-swizzled (byte ^= (row&7)<<4).
// Transform: 4 ntiles x 4 kslices of mfma_f32_16x16x32_bf16.
template <int SELF_F32, int RELU>
__global__ __launch_bounds__(256) void agg_tf(
    const unsigned short* __restrict__ src,   // [Ns][64] bf16
    const void* __restrict__ selfF,           // [N][64] f32 or bf16
    const int* __restrict__ off, const int* __restrict__ csr,
    const unsigned short* __restrict__ Wp,    // packed B-frags [16*64*8] bf16
    const float* __restrict__ bias,           // [64]
    unsigned short* __restrict__ out, int N) {
  __shared__ unsigned short A[4][16][128];    // 16 KB
  int t = threadIdx.x, wave = t >> 6, lane = t & 63;
  int nbase = (blockIdx.x * 4 + wave) * 16;
  if (nbase >= N) return;  // wave-local tile, no cross-wave deps
  char* rowbase = (char*)&A[wave][0][0];
  for (int g = 0; g < 16; ++g) {
    int n = nbase + g;
    float a = 0.f, sf = 0.f;
    if (n < N) {
      int beg = off[n], end = off[n + 1], k = beg;
      for (; k + 4 <= end; k += 4) {
        int s0 = csr[k], s1 = csr[k + 1], s2 = csr[k + 2], s3 = csr[k + 3];
        float a0 = bf2f(src[(size_t)s0 * 64 + lane]);
        float a1 = bf2f(src[(size_t)s1 * 64 + lane]);
        float a2 = bf2f(src[(size_t)s2 * 64 + lane]);
        float a3 = bf2f(src[(size_t)s3 * 64 + lane]);
        a += (a0 + a1) + (a2 + a3);
      }
      for (; k < end; ++k) a += bf2f(src[(size_t)csr[k] * 64 + lane]);
      a /= fmaxf((float)(end - beg), 1.f);  // segment mean (0 if empty)
      sf = SELF_F32 ? ((const float*)selfF)[(size_t)n * 64 + lane]
                    : bf2f(((const unsigned short*)selfF)[(size_t)n * 64 + lane]);
    }
    int swz = (g & 7) << 4;
    char* rp = rowbase + g * 256;
    *(unsigned short*)(rp + ((lane * 2) ^ swz)) = f2bf(a);          // cols 0..63
    *(unsigned short*)(rp + ((128 + lane * 2) ^ swz)) = f2bf(sf);   // cols 64..127
  }
  // wave-local LDS write->read: hardware lgkmcnt ordering, no barrier
  int r = lane & 15, q = lane >> 4;
  int swzr = (r & 7) << 4;
  const char* arow = rowbase + r * 256;
  short8 af[4];
#pragma unroll
  for (int ks = 0; ks < 4; ++ks)
    af[ks] = *(const short8*)(arow + ((ks * 64 + q * 16) ^ swzr));
  const short8* wp8 = (const short8*)Wp;
#pragma unroll
  for (int nt = 0; nt < 4; ++nt) {
    float b = bias[nt * 16 + r];
    f32x4 acc = {b, b, b, b};
#pragma unroll
    for (int ks = 0; ks < 4; ++ks) {
      short8 bf = wp8[(nt * 4 + ks) * 64 + lane];
      acc = __builtin_amdgcn_mfma_f32_16x16x32_bf16(af[ks], bf, acc, 0, 0, 0);
    }
#pragma unroll
    for (int j = 0; j < 4; ++j) {
      int n = nbase + q * 4 + j;           // C row = (lane>>4)*4 + j
      if (n < N) {
        float v = acc[j];
        if (RELU) v = fmaxf(v, 0.f);
        out[(size_t)n * 64 + nt * 16 + r] = f2bf(v);  // C col = nt*16 + (lane&15)
      }
    }
  }
}

// ---- edge classifier, EDGE order ------------------------------------------
__global__ __launch_bounds__(256) void edge_mlp(
    const unsigned short* __restrict__ pu, const unsigned short* __restrict__ pm,
    const int* __restrict__ u_idx, const int* __restrict__ m_idx,
    const float* __restrict__ w2, const float* __restrict__ bvec,
    float* __restrict__ out, int E) {
  int t = threadIdx.x;
  int lane = t & 63;
  int sub = lane >> 4;   // subgroup 0..3
  int fl = lane & 15;    // position in subgroup
  int f = fl * 4;        // features f..f+3
  int wid = (blockIdx.x * 256 + t) >> 6;
  int nw = (gridDim.x * 256) >> 6;
  float4 wA = reinterpret_cast<const float4*>(w2)[2 * fl];      // rows f, f+1
  float4 wB = reinterpret_cast<const float4*>(w2)[2 * fl + 1];  // rows f+2, f+3
  float ob0 = bvec[0], ob1 = bvec[1];
  int ngrp = (E + 3) >> 2;
  for (int g = wid; g < ngrp; g += nw) {
    int e = g * 4 + sub;
    bool valid = e < E;
    int ee = valid ? e : 0;
    int u = u_idx[ee], m = m_idx[ee];
    ushort4 a4 = *reinterpret_cast<const ushort4*>(&pu[(size_t)u * 64 + f]);
    ushort4 b4 = *reinterpret_cast<const ushort4*>(&pm[(size_t)m * 64 + f]);
    float v0 = fmaxf(bf2f(a4.x) + bf2f(b4.x), 0.f);
    float v1 = fmaxf(bf2f(a4.y) + bf2f(b4.y), 0.f);
    float v2 = fmaxf(bf2f(a4.z) + bf2f(b4.z), 0.f);
    float v3 = fmaxf(bf2f(a4.w) + bf2f(b4.w), 0.f);
    float a0 = v0 * wA.x + v1 * wA.z + v2 * wB.x + v3 * wB.z;
    float a1 = v0 * wA.y + v1 * wA.w + v2 * wB.y + v3 * wB.w;
#pragma unroll
    for (int o = 8; o; o >>= 1) { a0 += __shfl_xor(a0, o); a1 += __shfl_xor(a1, o); }
    if (valid && fl == 0) {
      *reinterpret_cast<float2*>(&out[(size_t)e * 2]) = make_float2(a0 + ob0, a1 + ob1);
    }
  }
}

extern "C" void kernel_launch(void* const* d_in, const int* in_sizes, int n_in,
                              void* d_out, int out_size, void* d_ws, size_t ws_size,
                              hipStream_t stream) {
  const float* x_user  = (const float*)d_in[0];
  const float* x_merch = (const float*)d_in[1];
  const float* bases1  = (const float*)d_in[2];
  const float* coeff1  = (const float*)d_in[3];
  const float* root1   = (const float*)d_in[4];
  const float* b1      = (const float*)d_in[5];
  const float* bases2  = (const float*)d_in[6];
  const float* coeff2  = (const float*)d_in[7];
  const float* root2   = (const float*)d_in[8];
  const float* b2      = (const float*)d_in[9];
  const float* w_mlp1  = (const float*)d_in[10];
  const float* b_mlp1  = (const float*)d_in[11];
  const float* w_mlp2  = (const float*)d_in[12];
  const float* b_mlp2  = (const float*)d_in[13];
  const int*   edge_ix = (const int*)d_in[14];

  const int Nu = in_sizes[0] / 64;
  const int Nm = in_sizes[1] / 64;
  const int E  = in_sizes[14] / 2;
  const int* u_idx = edge_ix;
  const int* m_idx = edge_ix + E;

  char* p = (char*)d_ws;
  auto alloc = [&](size_t bytes) -> char* {
    char* r = p;
    p += (bytes + 255) & ~(size_t)255;
    return r;
  };
  int* off_u = (int*)alloc((size_t)(Nu + 1) * 4);
  int* off_m = (int*)alloc((size_t)(Nm + 1) * 4);
  int* part  = (int*)alloc(512 * 4);
  int* csr_u = (int*)alloc((size_t)E * 4);   // merchants grouped by user
  int* csr_m = (int*)alloc((size_t)E * 4);   // users grouped by merchant
  unsigned short* xb_u = (unsigned short*)alloc((size_t)Nu * 64 * 2);  // also: stage_m alias; later pu
  unsigned short* xb_m = (unsigned short*)alloc((size_t)Nm * 64 * 2);  // later pm
  unsigned short* h_u  = (unsigned short*)alloc((size_t)Nu * 64 * 2);  // also: stage_u alias
  unsigned short* h_m  = (unsigned short*)alloc((size_t)Nm * 64 * 2);  // also: hist alias
  float* Wcat1u = (float*)alloc(8192 * 4);
  float* Wcat1m = (float*)alloc(8192 * 4);
  float* Wcat2u = (float*)alloc(8192 * 4);
  float* Wcat2m = (float*)alloc(8192 * 4);
  unsigned short* Wp1u = (unsigned short*)alloc(8192 * 2);
  unsigned short* Wp1m = (unsigned short*)alloc(8192 * 2);
  unsigned short* Wp2u = (unsigned short*)alloc(8192 * 2);
  unsigned short* Wp2m = (unsigned short*)alloc(8192 * 2);
  float* wp2 = (float*)alloc(4096 * 4);
  float* wr2 = (float*)alloc(4096 * 4);
  float* bu2 = (float*)alloc(64 * 4);
  float* bm2 = (float*)alloc(64 * 4);
  if ((size_t)(p - (char*)d_ws) > ws_size) return;

  const int nblk = (E + 2047) / 2048;
  const int nhist = 256 * nblk;
  // aliases (lifetimes: sorts complete before tobf16 / layer-1 agg writes)
  int*  hist_u  = (int*)h_m;
  int*  hist_m  = hist_u + nhist;
  int2* stage_u = (int2*)h_u;
  int2* stage_m = (int2*)xb_u;

  // ---- CSR build: 2-level bucket sort, zero global atomics ----
  sort_hist<<<nblk, 256, 0, stream>>>(u_idx, m_idx, hist_u, hist_m, E, nblk);
  int sb = (nhist + 2047) / 2048;
  scanA<<<sb, 256, 0, stream>>>(hist_u, hist_u, part, nhist);
  scanB<<<1, 256, 0, stream>>>(part, part + 400, sb);
  scanC<<<sb, 256, 0, stream>>>(hist_u, part, nhist);
  scanA<<<sb, 256, 0, stream>>>(hist_m, hist_m, part, nhist);
  scanB<<<1, 256, 0, stream>>>(part, part + 400, sb);
  scanC<<<sb, 256, 0, stream>>>(hist_m, part, nhist);
  sort_scatter1<<<nblk, 256, 0, stream>>>(u_idx, m_idx, hist_u, hist_m,
                                          stage_u, stage_m, E, nblk);
  sort_bucket<10><<<256, 256, 0, stream>>>(stage_u, hist_u, csr_u, off_u, E, Nu, nblk);
  sort_bucket<8><<<256, 256, 0, stream>>>(stage_m, hist_m, csr_m, off_m, E, Nm, nblk);

  // ---- feature tables & weights ----
  tobf16<<<1024, 256, 0, stream>>>(x_user, xb_u, Nu * 16);
  tobf16<<<256, 256, 0, stream>>>(x_merch, xb_m, Nm * 16);
  mkW1<<<16, 256, 0, stream>>>(bases1, coeff1, root1, bases2, coeff2,
                               Wcat1u, Wcat1m, wp2, wr2);
  mkW2<<<16, 256, 0, stream>>>(wp2, wr2, root2, w_mlp1, b2, b_mlp1,
                               Wcat2u, Wcat2m, bu2, bm2);
  packW4<<<128, 256, 0, stream>>>(Wcat1u, Wcat1m, Wcat2u, Wcat2m,
                                  Wp1u, Wp1m, Wp2u, Wp2m);

  int gbu = (Nu + 63) / 64, gbm = (Nm + 63) / 64;
  // layer 1 (relu): self from original f32 arrays
  agg_tf<1, 1><<<gbu, 256, 0, stream>>>(xb_m, x_user, off_u, csr_u, Wp1u, b1, h_u, Nu);
  agg_tf<1, 1><<<gbm, 256, 0, stream>>>(xb_u, x_merch, off_m, csr_m, Wp1m, b1, h_m, Nm);
  // layer 2 fused with edge-MLP left matrix; outputs reuse xb buffers
  unsigned short* pm_buf = xb_m;
  unsigned short* pu_buf = xb_u;
  agg_tf<0, 0><<<gbm, 256, 0, stream>>>(h_u, h_m, off_m, csr_m, Wp2m, bm2, pm_buf, Nm);
  agg_tf<0, 0><<<gbu, 256, 0, stream>>>(h_m, h_u, off_u, csr_u, Wp2u, bu2, pu_buf, Nu);

  edge_mlp<<<2048, 256, 0, stream>>>(pu_buf, pm_buf, u_idx, m_idx,
                                     w_mlp2, b_mlp2, (float*)d_out, E);
}

// Round 8
// 442.190 us; speedup vs baseline: 2.6692x; 1.5836x over previous
//
#include <hip/hip_runtime.h>

// ---------------------------------------------------------------------------
// Hetero-SAGE edge classifier.
//  Round-8: subgroup gather in agg_tf. R7 profile: agg_tf latency-bound
//  (VALU 19%, MFMA 0.2%, HBM 12%, occ 30%) — lane=feature layout gives only
//  ~4 outstanding row-gathers/wave. New: 16-lane subgroups (lane covers 4
//  features via ushort4), 4 nodes in flight per wave x unroll-4 degree loop
//  -> 16 outstanding gathers, ~3x fewer iteration slots. Layer-1 self reads
//  bf16 tables (-25MB fetch). MFMA transform + swizzled LDS unchanged.
//  CSR bucket sort / edge_mlp / weight prep unchanged from R7.
// ---------------------------------------------------------------------------

typedef __attribute__((ext_vector_type(8))) short short8;
typedef __attribute__((ext_vector_type(4))) float f32x4;

__device__ inline unsigned short f2bf(float f) {
  unsigned u = __float_as_uint(f);
  u += 0x7FFF + ((u >> 16) & 1);  // round-to-nearest-even
  return (unsigned short)(u >> 16);
}
__device__ inline float bf2f(unsigned short h) {
  return __uint_as_float(((unsigned)h) << 16);
}

__global__ void tobf16(const float* __restrict__ in, unsigned short* __restrict__ out, int n4) {
  int i = blockIdx.x * 256 + threadIdx.x;
  int stride = gridDim.x * 256;
  for (int j = i; j < n4; j += stride) {
    float4 v = reinterpret_cast<const float4*>(in)[j];
    ushort4 o;
    o.x = f2bf(v.x); o.y = f2bf(v.y); o.z = f2bf(v.z); o.w = f2bf(v.w);
    reinterpret_cast<ushort4*>(out)[j] = o;
  }
}

// ---- 3-phase exclusive scan (chunk = 2048 = 256 threads * 8 items) --------
__global__ void scanA(const int* __restrict__ cnt, int* __restrict__ off,
                      int* __restrict__ part, int N) {
  __shared__ int s[256];
  int t = threadIdx.x;
  int base = blockIdx.x * 2048 + t * 8;
  int v[8]; int sum = 0;
#pragma unroll
  for (int i = 0; i < 8; ++i) { int idx = base + i; v[i] = (idx < N) ? cnt[idx] : 0; sum += v[i]; }
  s[t] = sum;
  __syncthreads();
  for (int ofs = 1; ofs < 256; ofs <<= 1) {
    int a = (t >= ofs) ? s[t - ofs] : 0;
    __syncthreads();
    s[t] += a;
    __syncthreads();
  }
  int run = s[t] - sum;
#pragma unroll
  for (int i = 0; i < 8; ++i) { int idx = base + i; if (idx < N) off[idx] = run; run += v[i]; }
  if (t == 255) part[blockIdx.x] = s[255];
}

__global__ void scanB(int* __restrict__ part, int* __restrict__ off_last, int NB) {
  __shared__ int s[256];
  int t = threadIdx.x;
  int v = (t < NB) ? part[t] : 0;
  s[t] = v;
  __syncthreads();
  for (int ofs = 1; ofs < 256; ofs <<= 1) {
    int a = (t >= ofs) ? s[t - ofs] : 0;
    __syncthreads();
    s[t] += a;
    __syncthreads();
  }
  if (t < NB) part[t] = s[t] - v;
  if (t == NB - 1) off_last[0] = s[t];
}

__global__ void scanC(int* __restrict__ off, const int* __restrict__ part, int N) {
  int base = blockIdx.x * 2048 + threadIdx.x * 8;
  int add = part[blockIdx.x];
#pragma unroll
  for (int i = 0; i < 8; ++i) { int idx = base + i; if (idx < N) off[idx] += add; }
}

// ---- K1: per-chunk dual histogram of high digits (LDS atomics only) -------
__global__ __launch_bounds__(256) void sort_hist(
    const int* __restrict__ u_idx, const int* __restrict__ m_idx,
    int* __restrict__ hist_u, int* __restrict__ hist_m, int E, int nblk) {
  __shared__ int hu[256], hm[256];
  int t = threadIdx.x, blk = blockIdx.x;
  hu[t] = 0; hm[t] = 0;
  __syncthreads();
  int e0 = blk * 2048 + t;
#pragma unroll
  for (int i = 0; i < 8; ++i) {
    int e = e0 + i * 256;
    if (e < E) {
      atomicAdd(&hu[u_idx[e] >> 10], 1);
      atomicAdd(&hm[m_idx[e] >> 8], 1);
    }
  }
  __syncthreads();
  hist_u[t * nblk + blk] = hu[t];  // [bin][blk] layout for bucket-contiguous scan
  hist_m[t * nblk + blk] = hm[t];
}

// ---- K3: partition edges into high-digit buckets --------------------------
__global__ __launch_bounds__(256) void sort_scatter1(
    const int* __restrict__ u_idx, const int* __restrict__ m_idx,
    const int* __restrict__ base_u, const int* __restrict__ base_m,
    int2* __restrict__ stage_u, int2* __restrict__ stage_m, int E, int nblk) {
  __shared__ int cu[256], cm[256];
  int t = threadIdx.x, blk = blockIdx.x;
  cu[t] = base_u[t * nblk + blk];
  cm[t] = base_m[t * nblk + blk];
  __syncthreads();
  int e0 = blk * 2048 + t;
#pragma unroll
  for (int i = 0; i < 8; ++i) {
    int e = e0 + i * 256;
    if (e < E) {
      int u = u_idx[e], m = m_idx[e];
      int pu = atomicAdd(&cu[u >> 10], 1);
      stage_u[pu] = make_int2(u, m);
      int pm = atomicAdd(&cm[m >> 8], 1);
      stage_m[pm] = make_int2(m, u);
    }
  }
}

// ---- K4: block-per-bucket low-digit counting sort -------------------------
template <int LOWBITS>
__global__ __launch_bounds__(256) void sort_bucket(
    const int2* __restrict__ stage, const int* __restrict__ hs,
    int* __restrict__ vals_out, int* __restrict__ off,
    int E, int N, int nblk) {
  constexpr int NBIN = 1 << LOWBITS;
  constexpr int R = NBIN / 256;
  __shared__ int h[NBIN];
  __shared__ int s[256];
  int t = threadIdx.x, b = blockIdx.x;
  int seg0 = hs[b * nblk];
  int seg1 = (b == 255) ? E : hs[(b + 1) * nblk];
#pragma unroll
  for (int r = 0; r < R; ++r) h[t * R + r] = 0;
  __syncthreads();
  for (int i = seg0 + t; i < seg1; i += 256)
    atomicAdd(&h[stage[i].x & (NBIN - 1)], 1);
  __syncthreads();
  int vals[R]; int loc = 0;
#pragma unroll
  for (int r = 0; r < R; ++r) { vals[r] = h[t * R + r]; loc += vals[r]; }
  s[t] = loc;
  __syncthreads();
  for (int ofs = 1; ofs < 256; ofs <<= 1) {
    int a = (t >= ofs) ? s[t - ofs] : 0;
    __syncthreads();
    s[t] += a;
    __syncthreads();
  }
  int run = seg0 + s[t] - loc;
#pragma unroll
  for (int r = 0; r < R; ++r) {
    int bin = t * R + r;
    h[bin] = run;
    int node = (b << LOWBITS) + bin;
    if (node <= N) off[node] = run;   // segment start; node==N -> E
    run += vals[r];
  }
  __syncthreads();
  for (int i = seg0 + t; i < seg1; i += 256) {
    int2 v = stage[i];
    int pos = atomicAdd(&h[v.x & (NBIN - 1)], 1);
    vals_out[pos] = v.y;
  }
}

// ---- weight preparation ---------------------------------------------------
// Wcat layout: [128][64] row-major; rows 0..63 aggregate weight, 64..127 root.
__global__ void mkW1(const float* __restrict__ bases1, const float* __restrict__ coeff1,
                     const float* __restrict__ root1,
                     const float* __restrict__ bases2, const float* __restrict__ coeff2,
                     float* __restrict__ Wcat1u, float* __restrict__ Wcat1m,
                     float* __restrict__ wp2, float* __restrict__ wr2) {
  int ij = blockIdx.x * 256 + threadIdx.x;  // 0..4095
  float a0 = bases1[ij], a1 = bases1[4096 + ij], a2 = bases1[8192 + ij];
  Wcat1m[ij] = coeff1[0] * a0 + coeff1[1] * a1 + coeff1[2] * a2;  // W_pays1
  Wcat1u[ij] = coeff1[3] * a0 + coeff1[4] * a1 + coeff1[5] * a2;  // W_rev1
  float r = root1[ij];
  Wcat1m[4096 + ij] = r;
  Wcat1u[4096 + ij] = r;
  float c0 = bases2[ij], c1 = bases2[4096 + ij], c2 = bases2[8192 + ij];
  wp2[ij] = coeff2[0] * c0 + coeff2[1] * c1 + coeff2[2] * c2;
  wr2[ij] = coeff2[3] * c0 + coeff2[4] * c1 + coeff2[5] * c2;
}

__global__ void mkW2(const float* __restrict__ wp2, const float* __restrict__ wr2,
                     const float* __restrict__ root2, const float* __restrict__ w_mlp1,
                     const float* __restrict__ b2, const float* __restrict__ b_mlp1,
                     float* __restrict__ Wcat2u, float* __restrict__ Wcat2m,
                     float* __restrict__ bu2, float* __restrict__ bm2) {
  int tid = blockIdx.x * 256 + threadIdx.x;  // 0..4095
  int i = tid >> 6, j = tid & 63;
  float au = 0.f, ru = 0.f, am = 0.f, rm = 0.f;
  for (int k = 0; k < 64; ++k) {
    float wa = w_mlp1[k * 64 + j];
    float wb = w_mlp1[(64 + k) * 64 + j];
    au += wr2[i * 64 + k] * wa;
    ru += root2[i * 64 + k] * wa;
    am += wp2[i * 64 + k] * wb;
    rm += root2[i * 64 + k] * wb;
  }
  Wcat2u[tid] = au; Wcat2u[4096 + tid] = ru;
  Wcat2m[tid] = am; Wcat2m[4096 + tid] = rm;
  if (i == 0) {
    float s1 = 0.f, s2 = 0.f;
    for (int k = 0; k < 64; ++k) {
      s1 += b2[k] * w_mlp1[k * 64 + j];
      s2 += b2[k] * w_mlp1[(64 + k) * 64 + j];
    }
    bu2[j] = s1;
    bm2[j] = s2 + b_mlp1[j];
  }
}

// ---- pack Wcat [128][64] f32 into MFMA B-fragment layout, bf16 ------------
__global__ void packW4(const float* __restrict__ s0, const float* __restrict__ s1,
                       const float* __restrict__ s2, const float* __restrict__ s3,
                       unsigned short* __restrict__ d0, unsigned short* __restrict__ d1,
                       unsigned short* __restrict__ d2, unsigned short* __restrict__ d3) {
  int gid = blockIdx.x * 256 + threadIdx.x;   // 0..32767
  int mat = gid >> 13;                        // 0..3
  int tid = gid & 8191;
  int frag = tid >> 9;
  int nt = frag >> 2, ks = frag & 3;
  int lane = (tid >> 3) & 63;
  int i = tid & 7;
  int k = ks * 32 + (lane >> 4) * 8 + i;
  int col = nt * 16 + (lane & 15);
  const float* s = (mat == 0) ? s0 : (mat == 1) ? s1 : (mat == 2) ? s2 : s3;
  unsigned short* d = (mat == 0) ? d0 : (mat == 1) ? d1 : (mat == 2) ? d2 : d3;
  d[tid] = f2bf(s[k * 64 + col]);
}

// ---- fused segment-mean + MFMA transform + bias (+relu) -------------------
// block = 256 = 4 waves; wave owns 16 nodes.
// Gather: 16-lane subgroups — lane fl=lane&15 covers features 4fl..4fl+3
// (ushort4); subgroup sub=lane>>4 processes nodes nbase+sub*4+j, unroll-4
// over edges -> 16 outstanding row-gathers per wave.
// A-tile [16][128] bf16 in LDS, XOR-swizzled (byte ^= (row&7)<<4).
// Transform: 4 ntiles x 4 kslices of mfma_f32_16x16x32_bf16.
template <int RELU>
__global__ __launch_bounds__(256) void agg_tf(
    const unsigned short* __restrict__ src,   // [Ns][64] bf16
    const unsigned short* __restrict__ selfF, // [N][64] bf16
    const int* __restrict__ off, const int* __restrict__ csr,
    const unsigned short* __restrict__ Wp,    // packed B-frags [16*64*8] bf16
    const float* __restrict__ bias,           // [64]
    unsigned short* __restrict__ out, int N) {
  __shared__ unsigned short A[4][16][128];    // 16 KB
  int t = threadIdx.x, wave = t >> 6, lane = t & 63;
  int nbase = (blockIdx.x * 4 + wave) * 16;
  if (nbase >= N) return;  // wave-local tile, no cross-wave deps
  int fl = lane & 15, sub = lane >> 4;
  const ushort4* src4 = (const ushort4*)src;
  char* rowbase = (char*)&A[wave][0][0];
#pragma unroll 1
  for (int j = 0; j < 4; ++j) {
    int g = sub * 4 + j;
    int n = nbase + g;
    float ax = 0.f, ay = 0.f, az = 0.f, aw = 0.f;
    float inv = 1.f;
    ushort4 sf4 = make_ushort4(0, 0, 0, 0);
    if (n < N) {
      int beg = off[n], end = off[n + 1], k = beg;
      for (; k + 4 <= end; k += 4) {
        int s0 = csr[k], s1 = csr[k + 1], s2 = csr[k + 2], s3 = csr[k + 3];
        ushort4 r0 = src4[(size_t)s0 * 16 + fl];
        ushort4 r1 = src4[(size_t)s1 * 16 + fl];
        ushort4 r2 = src4[(size_t)s2 * 16 + fl];
        ushort4 r3 = src4[(size_t)s3 * 16 + fl];
        ax += (bf2f(r0.x) + bf2f(r1.x)) + (bf2f(r2.x) + bf2f(r3.x));
        ay += (bf2f(r0.y) + bf2f(r1.y)) + (bf2f(r2.y) + bf2f(r3.y));
        az += (bf2f(r0.z) + bf2f(r1.z)) + (bf2f(r2.z) + bf2f(r3.z));
        aw += (bf2f(r0.w) + bf2f(r1.w)) + (bf2f(r2.w) + bf2f(r3.w));
      }
      for (; k < end; ++k) {
        ushort4 r = src4[(size_t)csr[k] * 16 + fl];
        ax += bf2f(r.x); ay += bf2f(r.y); az += bf2f(r.z); aw += bf2f(r.w);
      }
      inv = 1.f / fmaxf((float)(end - beg), 1.f);
      sf4 = *reinterpret_cast<const ushort4*>(&selfF[(size_t)n * 64 + fl * 4]);
    }
    ushort4 ab;
    ab.x = f2bf(ax * inv); ab.y = f2bf(ay * inv);
    ab.z = f2bf(az * inv); ab.w = f2bf(aw * inv);
    int swz = (g & 7) << 4;
    char* rp = rowbase + g * 256;
    *(ushort4*)(rp + ((fl * 8) ^ swz)) = ab;          // cols 0..63  (agg)
    *(ushort4*)(rp + ((128 + fl * 8) ^ swz)) = sf4;   // cols 64..127 (self)
  }
  // wave-local LDS write->read: compiler lgkmcnt ordering, no barrier
  int r = lane & 15, q = lane >> 4;
  int swzr = (r & 7) << 4;
  const char* arow = rowbase + r * 256;
  short8 af[4];
#pragma unroll
  for (int ks = 0; ks < 4; ++ks)
    af[ks] = *(const short8*)(arow + ((ks * 64 + q * 16) ^ swzr));
  const short8* wp8 = (const short8*)Wp;
#pragma unroll
  for (int nt = 0; nt < 4; ++nt) {
    float b = bias[nt * 16 + r];
    f32x4 acc = {b, b, b, b};
#pragma unroll
    for (int ks = 0; ks < 4; ++ks) {
      short8 bf = wp8[(nt * 4 + ks) * 64 + lane];
      acc = __builtin_amdgcn_mfma_f32_16x16x32_bf16(af[ks], bf, acc, 0, 0, 0);
    }
#pragma unroll
    for (int j = 0; j < 4; ++j) {
      int n = nbase + q * 4 + j;           // C row = (lane>>4)*4 + j
      if (n < N) {
        float v = acc[j];
        if (RELU) v = fmaxf(v, 0.f);
        out[(size_t)n * 64 + nt * 16 + r] = f2bf(v);  // C col = nt*16 + (lane&15)
      }
    }
  }
}

// ---- edge classifier, EDGE order ------------------------------------------
__global__ __launch_bounds__(256) void edge_mlp(
    const unsigned short* __restrict__ pu, const unsigned short* __restrict__ pm,
    const int* __restrict__ u_idx, const int* __restrict__ m_idx,
    const float* __restrict__ w2, const float* __restrict__ bvec,
    float* __restrict__ out, int E) {
  int t = threadIdx.x;
  int lane = t & 63;
  int sub = lane >> 4;   // subgroup 0..3
  int fl = lane & 15;    // position in subgroup
  int f = fl * 4;        // features f..f+3
  int wid = (blockIdx.x * 256 + t) >> 6;
  int nw = (gridDim.x * 256) >> 6;
  float4 wA = reinterpret_cast<const float4*>(w2)[2 * fl];      // rows f, f+1
  float4 wB = reinterpret_cast<const float4*>(w2)[2 * fl + 1];  // rows f+2, f+3
  float ob0 = bvec[0], ob1 = bvec[1];
  int ngrp = (E + 3) >> 2;
  for (int g = wid; g < ngrp; g += nw) {
    int e = g * 4 + sub;
    bool valid = e < E;
    int ee = valid ? e : 0;
    int u = u_idx[ee], m = m_idx[ee];
    ushort4 a4 = *reinterpret_cast<const ushort4*>(&pu[(size_t)u * 64 + f]);
    ushort4 b4 = *reinterpret_cast<const ushort4*>(&pm[(size_t)m * 64 + f]);
    float v0 = fmaxf(bf2f(a4.x) + bf2f(b4.x), 0.f);
    float v1 = fmaxf(bf2f(a4.y) + bf2f(b4.y), 0.f);
    float v2 = fmaxf(bf2f(a4.z) + bf2f(b4.z), 0.f);
    float v3 = fmaxf(bf2f(a4.w) + bf2f(b4.w), 0.f);
    float a0 = v0 * wA.x + v1 * wA.z + v2 * wB.x + v3 * wB.z;
    float a1 = v0 * wA.y + v1 * wA.w + v2 * wB.y + v3 * wB.w;
#pragma unroll
    for (int o = 8; o; o >>= 1) { a0 += __shfl_xor(a0, o); a1 += __shfl_xor(a1, o); }
    if (valid && fl == 0) {
      *reinterpret_cast<float2*>(&out[(size_t)e * 2]) = make_float2(a0 + ob0, a1 + ob1);
    }
  }
}

extern "C" void kernel_launch(void* const* d_in, const int* in_sizes, int n_in,
                              void* d_out, int out_size, void* d_ws, size_t ws_size,
                              hipStream_t stream) {
  const float* x_user  = (const float*)d_in[0];
  const float* x_merch = (const float*)d_in[1];
  const float* bases1  = (const float*)d_in[2];
  const float* coeff1  = (const float*)d_in[3];
  const float* root1   = (const float*)d_in[4];
  const float* b1      = (const float*)d_in[5];
  const float* bases2  = (const float*)d_in[6];
  const float* coeff2  = (const float*)d_in[7];
  const float* root2   = (const float*)d_in[8];
  const float* b2      = (const float*)d_in[9];
  const float* w_mlp1  = (const float*)d_in[10];
  const float* b_mlp1  = (const float*)d_in[11];
  const float* w_mlp2  = (const float*)d_in[12];
  const float* b_mlp2  = (const float*)d_in[13];
  const int*   edge_ix = (const int*)d_in[14];

  const int Nu = in_sizes[0] / 64;
  const int Nm = in_sizes[1] / 64;
  const int E  = in_sizes[14] / 2;
  const int* u_idx = edge_ix;
  const int* m_idx = edge_ix + E;

  char* p = (char*)d_ws;
  auto alloc = [&](size_t bytes) -> char* {
    char* r = p;
    p += (bytes + 255) & ~(size_t)255;
    return r;
  };
  int* off_u = (int*)alloc((size_t)(Nu + 1) * 4);
  int* off_m = (int*)alloc((size_t)(Nm + 1) * 4);
  int* part  = (int*)alloc(512 * 4);
  int* csr_u = (int*)alloc((size_t)E * 4);   // merchants grouped by user
  int* csr_m = (int*)alloc((size_t)E * 4);   // users grouped by merchant
  unsigned short* xb_u = (unsigned short*)alloc((size_t)Nu * 64 * 2);  // also: stage_m alias; later pu
  unsigned short* xb_m = (unsigned short*)alloc((size_t)Nm * 64 * 2);  // later pm
  unsigned short* h_u  = (unsigned short*)alloc((size_t)Nu * 64 * 2);  // also: stage_u alias
  unsigned short* h_m  = (unsigned short*)alloc((size_t)Nm * 64 * 2);  // also: hist alias
  float* Wcat1u = (float*)alloc(8192 * 4);
  float* Wcat1m = (float*)alloc(8192 * 4);
  float* Wcat2u = (float*)alloc(8192 * 4);
  float* Wcat2m = (float*)alloc(8192 * 4);
  unsigned short* Wp1u = (unsigned short*)alloc(8192 * 2);
  unsigned short* Wp1m = (unsigned short*)alloc(8192 * 2);
  unsigned short* Wp2u = (unsigned short*)alloc(8192 * 2);
  unsigned short* Wp2m = (unsigned short*)alloc(8192 * 2);
  float* wp2 = (float*)alloc(4096 * 4);
  float* wr2 = (float*)alloc(4096 * 4);
  float* bu2 = (float*)alloc(64 * 4);
  float* bm2 = (float*)alloc(64 * 4);
  if ((size_t)(p - (char*)d_ws) > ws_size) return;

  const int nblk = (E + 2047) / 2048;
  const int nhist = 256 * nblk;
  // aliases (lifetimes: sorts complete before tobf16 / layer-1 agg writes)
  int*  hist_u  = (int*)h_m;
  int*  hist_m  = hist_u + nhist;
  int2* stage_u = (int2*)h_u;
  int2* stage_m = (int2*)xb_u;

  // ---- CSR build: 2-level bucket sort, zero global atomics ----
  sort_hist<<<nblk, 256, 0, stream>>>(u_idx, m_idx, hist_u, hist_m, E, nblk);
  int sb = (nhist + 2047) / 2048;
  scanA<<<sb, 256, 0, stream>>>(hist_u, hist_u, part, nhist);
  scanB<<<1, 256, 0, stream>>>(part, part + 400, sb);
  scanC<<<sb, 256, 0, stream>>>(hist_u, part, nhist);
  scanA<<<sb, 256, 0, stream>>>(hist_m, hist_m, part, nhist);
  scanB<<<1, 256, 0, stream>>>(part, part + 400, sb);
  scanC<<<sb, 256, 0, stream>>>(hist_m, part, nhist);
  sort_scatter1<<<nblk, 256, 0, stream>>>(u_idx, m_idx, hist_u, hist_m,
                                          stage_u, stage_m, E, nblk);
  sort_bucket<10><<<256, 256, 0, stream>>>(stage_u, hist_u, csr_u, off_u, E, Nu, nblk);
  sort_bucket<8><<<256, 256, 0, stream>>>(stage_m, hist_m, csr_m, off_m, E, Nm, nblk);

  // ---- feature tables & weights ----
  tobf16<<<1024, 256, 0, stream>>>(x_user, xb_u, Nu * 16);
  tobf16<<<256, 256, 0, stream>>>(x_merch, xb_m, Nm * 16);
  mkW1<<<16, 256, 0, stream>>>(bases1, coeff1, root1, bases2, coeff2,
                               Wcat1u, Wcat1m, wp2, wr2);
  mkW2<<<16, 256, 0, stream>>>(wp2, wr2, root2, w_mlp1, b2, b_mlp1,
                               Wcat2u, Wcat2m, bu2, bm2);
  packW4<<<128, 256, 0, stream>>>(Wcat1u, Wcat1m, Wcat2u, Wcat2m,
                                  Wp1u, Wp1m, Wp2u, Wp2m);

  int gbu = (Nu + 63) / 64, gbm = (Nm + 63) / 64;
  // layer 1 (relu): self from bf16 tables
  agg_tf<1><<<gbu, 256, 0, stream>>>(xb_m, xb_u, off_u, csr_u, Wp1u, b1, h_u, Nu);
  agg_tf<1><<<gbm, 256, 0, stream>>>(xb_u, xb_m, off_m, csr_m, Wp1m, b1, h_m, Nm);
  // layer 2 fused with edge-MLP left matrix; outputs reuse xb buffers
  unsigned short* pm_buf = xb_m;
  unsigned short* pu_buf = xb_u;
  agg_tf<0><<<gbm, 256, 0, stream>>>(h_u, h_m, off_m, csr_m, Wp2m, bm2, pm_buf, Nm);
  agg_tf<0><<<gbu, 256, 0, stream>>>(h_m, h_u, off_u, csr_u, Wp2u, bu2, pu_buf, Nu);

  edge_mlp<<<2048, 256, 0, stream>>>(pu_buf, pm_buf, u_idx, m_idx,
                                     w_mlp2, b_mlp2, (float*)d_out, E);
}

// Round 9
// 359.678 us; speedup vs baseline: 3.2815x; 1.2294x over previous
//
#include <hip/hip_runtime.h>

// ---------------------------------------------------------------------------
// Hetero-SAGE edge classifier.
//  Round-9: launch fusion + ILP. R8: edge_mlp 81us @3TB/s (random-line
//  pattern ceiling); remaining ~360us spread over 16 serialized dispatches.
//  (a) agg_dual: fuse the two independent agg_tf of each layer into one
//      launch (blockIdx split) -> gathers from 25.6MB and 6.4MB tables mix.
//  (b) piggyback mkW1/mkW2/packW4 onto sort launches; fuse u/m scan pairs,
//      both sort_buckets, both tobf16s. 17 launches -> 10.
//  (c) agg gather: 8-lane subgroups (short8) -> 32 outstanding rows/wave.
//  (d) edge_mlp: unroll x2 (4 outstanding gathers/lane), NT index loads.
// ---------------------------------------------------------------------------

typedef __attribute__((ext_vector_type(8))) short short8;
typedef __attribute__((ext_vector_type(4))) float f32x4;

__device__ inline unsigned short f2bf(float f) {
  unsigned u = __float_as_uint(f);
  u += 0x7FFF + ((u >> 16) & 1);  // round-to-nearest-even
  return (unsigned short)(u >> 16);
}
__device__ inline float bf2f(unsigned short h) {
  return __uint_as_float(((unsigned)h) << 16);
}
__device__ inline float bf2fs(short h) { return bf2f((unsigned short)h); }

// ---- fused bf16 conversion for both tables --------------------------------
__global__ __launch_bounds__(256) void tobf16_2(
    const float* __restrict__ a, unsigned short* __restrict__ oa, int n4a,
    const float* __restrict__ b, unsigned short* __restrict__ ob, int n4b) {
  int i = blockIdx.x * 256 + threadIdx.x;
  int stride = gridDim.x * 256;
  int tot = n4a + n4b;
  for (int j = i; j < tot; j += stride) {
    float4 v = (j < n4a) ? reinterpret_cast<const float4*>(a)[j]
                         : reinterpret_cast<const float4*>(b)[j - n4a];
    ushort4 o;
    o.x = f2bf(v.x); o.y = f2bf(v.y); o.z = f2bf(v.z); o.w = f2bf(v.w);
    if (j < n4a) reinterpret_cast<ushort4*>(oa)[j] = o;
    else reinterpret_cast<ushort4*>(ob)[j - n4a] = o;
  }
}

// ---- K1: per-chunk dual histogram (+ piggybacked mkW1) --------------------
__global__ __launch_bounds__(256) void sort_hist_mkW1(
    const int* __restrict__ u_idx, const int* __restrict__ m_idx,
    int* __restrict__ hist_u, int* __restrict__ hist_m, int E, int nblk,
    const float* __restrict__ bases1, const float* __restrict__ coeff1,
    const float* __restrict__ root1,
    const float* __restrict__ bases2, const float* __restrict__ coeff2,
    float* __restrict__ Wcat1u, float* __restrict__ Wcat1m,
    float* __restrict__ wp2, float* __restrict__ wr2) {
  int t = threadIdx.x, blk = blockIdx.x;
  if (blk >= nblk) {  // 16 trailing blocks: mkW1 (independent weight prep)
    int ij = (blk - nblk) * 256 + t;  // 0..4095
    float a0 = bases1[ij], a1 = bases1[4096 + ij], a2 = bases1[8192 + ij];
    Wcat1m[ij] = coeff1[0] * a0 + coeff1[1] * a1 + coeff1[2] * a2;  // W_pays1
    Wcat1u[ij] = coeff1[3] * a0 + coeff1[4] * a1 + coeff1[5] * a2;  // W_rev1
    float r = root1[ij];
    Wcat1m[4096 + ij] = r;
    Wcat1u[4096 + ij] = r;
    float c0 = bases2[ij], c1 = bases2[4096 + ij], c2 = bases2[8192 + ij];
    wp2[ij] = coeff2[0] * c0 + coeff2[1] * c1 + coeff2[2] * c2;
    wr2[ij] = coeff2[3] * c0 + coeff2[4] * c1 + coeff2[5] * c2;
    return;
  }
  __shared__ int hu[256], hm[256];
  hu[t] = 0; hm[t] = 0;
  __syncthreads();
  int e0 = blk * 2048 + t;
#pragma unroll
  for (int i = 0; i < 8; ++i) {
    int e = e0 + i * 256;
    if (e < E) {
      atomicAdd(&hu[u_idx[e] >> 10], 1);
      atomicAdd(&hm[m_idx[e] >> 8], 1);
    }
  }
  __syncthreads();
  hist_u[t * nblk + blk] = hu[t];  // [bin][blk] layout
  hist_m[t * nblk + blk] = hm[t];
}

// ---- scanA for both hists (+ piggybacked mkW2) ----------------------------
__global__ __launch_bounds__(256) void scanA2_mkW2(
    int* __restrict__ hist_u, int* __restrict__ hist_m,
    int* __restrict__ part, int nhist, int sb,
    const float* __restrict__ wp2, const float* __restrict__ wr2,
    const float* __restrict__ root2, const float* __restrict__ w_mlp1,
    const float* __restrict__ b2, const float* __restrict__ b_mlp1,
    float* __restrict__ Wcat2u, float* __restrict__ Wcat2m,
    float* __restrict__ bu2, float* __restrict__ bm2) {
  int blk = blockIdx.x;
  if (blk >= 2 * sb) {  // 16 trailing blocks: mkW2 (needs mkW1 from prev launch)
    int tid = (blk - 2 * sb) * 256 + threadIdx.x;  // 0..4095
    int i = tid >> 6, j = tid & 63;
    float au = 0.f, ru = 0.f, am = 0.f, rm = 0.f;
    for (int k = 0; k < 64; ++k) {
      float wa = w_mlp1[k * 64 + j];
      float wb = w_mlp1[(64 + k) * 64 + j];
      au += wr2[i * 64 + k] * wa;
      ru += root2[i * 64 + k] * wa;
      am += wp2[i * 64 + k] * wb;
      rm += root2[i * 64 + k] * wb;
    }
    Wcat2u[tid] = au; Wcat2u[4096 + tid] = ru;
    Wcat2m[tid] = am; Wcat2m[4096 + tid] = rm;
    if (i == 0) {
      float s1 = 0.f, s2 = 0.f;
      for (int k = 0; k < 64; ++k) {
        s1 += b2[k] * w_mlp1[k * 64 + j];
        s2 += b2[k] * w_mlp1[(64 + k) * 64 + j];
      }
      bu2[j] = s1;
      bm2[j] = s2 + b_mlp1[j];
    }
    return;
  }
  int* arr; int* prt;
  if (blk < sb) { arr = hist_u; prt = part; }
  else { arr = hist_m; prt = part + 256; blk -= sb; }
  __shared__ int s[256];
  int t = threadIdx.x;
  int base = blk * 2048 + t * 8;
  int v[8]; int sum = 0;
#pragma unroll
  for (int i = 0; i < 8; ++i) { int idx = base + i; v[i] = (idx < nhist) ? arr[idx] : 0; sum += v[i]; }
  s[t] = sum;
  __syncthreads();
  for (int ofs = 1; ofs < 256; ofs <<= 1) {
    int a = (t >= ofs) ? s[t - ofs] : 0;
    __syncthreads();
    s[t] += a;
    __syncthreads();
  }
  int run = s[t] - sum;
#pragma unroll
  for (int i = 0; i < 8; ++i) { int idx = base + i; if (idx < nhist) arr[idx] = run; run += v[i]; }
  if (t == 255) prt[blk] = s[255];
}

// ---- scanB for both partial arrays (+ piggybacked packW4) -----------------
__global__ __launch_bounds__(256) void scanB2_packW4(
    int* __restrict__ part, int NB,
    const float* __restrict__ s0, const float* __restrict__ s1,
    const float* __restrict__ s2, const float* __restrict__ s3,
    unsigned short* __restrict__ d0, unsigned short* __restrict__ d1,
    unsigned short* __restrict__ d2, unsigned short* __restrict__ d3) {
  int blk = blockIdx.x;
  if (blk >= 2) {  // 128 trailing blocks: packW4 (needs mkW1+mkW2 done)
    int gid = (blk - 2) * 256 + threadIdx.x;   // 0..32767
    int mat = gid >> 13;
    int tid = gid & 8191;
    int frag = tid >> 9;
    int nt = frag >> 2, ks = frag & 3;
    int lane = (tid >> 3) & 63;
    int i = tid & 7;
    int k = ks * 32 + (lane >> 4) * 8 + i;
    int col = nt * 16 + (lane & 15);
    const float* s = (mat == 0) ? s0 : (mat == 1) ? s1 : (mat == 2) ? s2 : s3;
    unsigned short* d = (mat == 0) ? d0 : (mat == 1) ? d1 : (mat == 2) ? d2 : d3;
    d[tid] = f2bf(s[k * 64 + col]);
    return;
  }
  int* prt = part + blk * 256;
  __shared__ int s[256];
  int t = threadIdx.x;
  int v = (t < NB) ? prt[t] : 0;
  s[t] = v;
  __syncthreads();
  for (int ofs = 1; ofs < 256; ofs <<= 1) {
    int a = (t >= ofs) ? s[t - ofs] : 0;
    __syncthreads();
    s[t] += a;
    __syncthreads();
  }
  if (t < NB) prt[t] = s[t] - v;
}

// ---- scanC for both hists -------------------------------------------------
__global__ __launch_bounds__(256) void scanC2(
    int* __restrict__ hist_u, int* __restrict__ hist_m,
    const int* __restrict__ part, int nhist, int sb) {
  int blk = blockIdx.x;
  int* off; const int* prt;
  if (blk < sb) { off = hist_u; prt = part; }
  else { off = hist_m; prt = part + 256; blk -= sb; }
  int base = blk * 2048 + threadIdx.x * 8;
  int add = prt[blk];
#pragma unroll
  for (int i = 0; i < 8; ++i) { int idx = base + i; if (idx < nhist) off[idx] += add; }
}

// ---- K3: partition edges into high-digit buckets --------------------------
__global__ __launch_bounds__(256) void sort_scatter1(
    const int* __restrict__ u_idx, const int* __restrict__ m_idx,
    const int* __restrict__ base_u, const int* __restrict__ base_m,
    int2* __restrict__ stage_u, int2* __restrict__ stage_m, int E, int nblk) {
  __shared__ int cu[256], cm[256];
  int t = threadIdx.x, blk = blockIdx.x;
  cu[t] = base_u[t * nblk + blk];
  cm[t] = base_m[t * nblk + blk];
  __syncthreads();
  int e0 = blk * 2048 + t;
#pragma unroll
  for (int i = 0; i < 8; ++i) {
    int e = e0 + i * 256;
    if (e < E) {
      int u = u_idx[e], m = m_idx[e];
      int pu = atomicAdd(&cu[u >> 10], 1);
      stage_u[pu] = make_int2(u, m);
      int pm = atomicAdd(&cm[m >> 8], 1);
      stage_m[pm] = make_int2(m, u);
    }
  }
}

// ---- K4: block-per-bucket low-digit counting sort (both CSRs, one launch) -
template <int LOWBITS>
__device__ __forceinline__ void bucket_body(
    const int2* __restrict__ stage, const int* __restrict__ hs,
    int* __restrict__ vals_out, int* __restrict__ off,
    int E, int N, int nblk, int b) {
  constexpr int NBIN = 1 << LOWBITS;
  constexpr int R = NBIN / 256;
  __shared__ int h[NBIN];
  __shared__ int s[256];
  int t = threadIdx.x;
  int seg0 = hs[b * nblk];
  int seg1 = (b == 255) ? E : hs[(b + 1) * nblk];
#pragma unroll
  for (int r = 0; r < R; ++r) h[t * R + r] = 0;
  __syncthreads();
  for (int i = seg0 + t; i < seg1; i += 256)
    atomicAdd(&h[stage[i].x & (NBIN - 1)], 1);
  __syncthreads();
  int vals[R]; int loc = 0;
#pragma unroll
  for (int r = 0; r < R; ++r) { vals[r] = h[t * R + r]; loc += vals[r]; }
  s[t] = loc;
  __syncthreads();
  for (int ofs = 1; ofs < 256; ofs <<= 1) {
    int a = (t >= ofs) ? s[t - ofs] : 0;
    __syncthreads();
    s[t] += a;
    __syncthreads();
  }
  int run = seg0 + s[t] - loc;
#pragma unroll
  for (int r = 0; r < R; ++r) {
    int bin = t * R + r;
    h[bin] = run;
    int node = (b << LOWBITS) + bin;
    if (node <= N) off[node] = run;   // segment start; node==N -> E
    run += vals[r];
  }
  __syncthreads();
  for (int i = seg0 + t; i < seg1; i += 256) {
    int2 v = stage[i];
    int pos = atomicAdd(&h[v.x & (NBIN - 1)], 1);
    vals_out[pos] = v.y;
  }
}

__global__ __launch_bounds__(256) void sort_bucket2(
    const int2* __restrict__ stage_u, const int* __restrict__ hist_u,
    int* __restrict__ csr_u, int* __restrict__ off_u, int Nu,
    const int2* __restrict__ stage_m, const int* __restrict__ hist_m,
    int* __restrict__ csr_m, int* __restrict__ off_m, int Nm,
    int E, int nblk) {
  if (blockIdx.x < 256)
    bucket_body<10>(stage_u, hist_u, csr_u, off_u, E, Nu, nblk, blockIdx.x);
  else
    bucket_body<8>(stage_m, hist_m, csr_m, off_m, E, Nm, nblk, blockIdx.x - 256);
}

// ---- fused segment-mean + MFMA transform + bias (+relu) -------------------
// wave owns 16 nodes; gather: 8-lane subgroups (short8 = 16B/lane, 8 lanes =
// one 128B row), 8 subgroups x 2 nodes x unroll-4 -> 32 outstanding rows.
// A-tile [16][128] bf16 in LDS, XOR-swizzled (byte ^= (row&7)<<4).
template <int RELU>
__device__ __forceinline__ void agg_body(
    const unsigned short* __restrict__ src,   // [Ns][64] bf16
    const unsigned short* __restrict__ selfF, // [N][64] bf16
    const int* __restrict__ off, const int* __restrict__ csr,
    const unsigned short* __restrict__ Wp,    // packed B-frags [16*64*8] bf16
    const float* __restrict__ bias,           // [64]
    unsigned short* __restrict__ out, int N, int blk) {
  __shared__ unsigned short A[4][16][128];    // 16 KB
  int t = threadIdx.x, wave = t >> 6, lane = t & 63;
  int nbase = (blk * 4 + wave) * 16;
  if (nbase >= N) return;  // wave-local tile, no cross-wave deps
  int fl = lane & 7, sub = lane >> 3;
  const short8* src8 = (const short8*)src;
  char* rowbase = (char*)&A[wave][0][0];
#pragma unroll 1
  for (int j = 0; j < 2; ++j) {
    int g = sub * 2 + j;
    int n = nbase + g;
    float ac[8] = {0.f, 0.f, 0.f, 0.f, 0.f, 0.f, 0.f, 0.f};
    float inv = 1.f;
    short8 sf8 = {0, 0, 0, 0, 0, 0, 0, 0};
    if (n < N) {
      int beg = off[n], end = off[n + 1], k = beg;
      for (; k + 4 <= end; k += 4) {
        int s0 = csr[k], s1 = csr[k + 1], s2 = csr[k + 2], s3 = csr[k + 3];
        short8 r0 = src8[(size_t)s0 * 8 + fl];
        short8 r1 = src8[(size_t)s1 * 8 + fl];
        short8 r2 = src8[(size_t)s2 * 8 + fl];
        short8 r3 = src8[(size_t)s3 * 8 + fl];
#pragma unroll
        for (int c = 0; c < 8; ++c)
          ac[c] += (bf2fs(r0[c]) + bf2fs(r1[c])) + (bf2fs(r2[c]) + bf2fs(r3[c]));
      }
      for (; k < end; ++k) {
        short8 r = src8[(size_t)csr[k] * 8 + fl];
#pragma unroll
        for (int c = 0; c < 8; ++c) ac[c] += bf2fs(r[c]);
      }
      inv = 1.f / fmaxf((float)(end - beg), 1.f);
      sf8 = ((const short8*)selfF)[(size_t)n * 8 + fl];
    }
    short8 ab;
#pragma unroll
    for (int c = 0; c < 8; ++c) ab[c] = (short)f2bf(ac[c] * inv);
    int swz = (g & 7) << 4;
    char* rp = rowbase + g * 256;
    *(short8*)(rp + ((fl * 16) ^ swz)) = ab;          // cols 0..63  (agg)
    *(short8*)(rp + ((128 + fl * 16) ^ swz)) = sf8;   // cols 64..127 (self)
  }
  // wave-local LDS write->read: compiler lgkmcnt ordering, no barrier
  int r = lane & 15, q = lane >> 4;
  int swzr = (r & 7) << 4;
  const char* arow = rowbase + r * 256;
  short8 af[4];
#pragma unroll
  for (int ks = 0; ks < 4; ++ks)
    af[ks] = *(const short8*)(arow + ((ks * 64 + q * 16) ^ swzr));
  const short8* wp8 = (const short8*)Wp;
#pragma unroll
  for (int nt = 0; nt < 4; ++nt) {
    float b = bias[nt * 16 + r];
    f32x4 acc = {b, b, b, b};
#pragma unroll
    for (int ks = 0; ks < 4; ++ks) {
      short8 bf = wp8[(nt * 4 + ks) * 64 + lane];
      acc = __builtin_amdgcn_mfma_f32_16x16x32_bf16(af[ks], bf, acc, 0, 0, 0);
    }
#pragma unroll
    for (int j = 0; j < 4; ++j) {
      int n = nbase + q * 4 + j;           // C row = (lane>>4)*4 + j
      if (n < N) {
        float v = acc[j];
        if (RELU) v = fmaxf(v, 0.f);
        out[(size_t)n * 64 + nt * 16 + r] = f2bf(v);  // C col = nt*16 + (lane&15)
      }
    }
  }
}

// Two independent agg passes fused into one launch (blockIdx split).
template <int RELU>
__global__ __launch_bounds__(256) void agg_dual(
    const unsigned short* __restrict__ srcA, const unsigned short* __restrict__ selfA,
    const int* __restrict__ offA, const int* __restrict__ csrA,
    const unsigned short* __restrict__ WpA, const float* __restrict__ biasA,
    unsigned short* __restrict__ outA, int NA, int gbA,
    const unsigned short* __restrict__ srcB, const unsigned short* __restrict__ selfB,
    const int* __restrict__ offB, const int* __restrict__ csrB,
    const unsigned short* __restrict__ WpB, const float* __restrict__ biasB,
    unsigned short* __restrict__ outB, int NB) {
  int blk = blockIdx.x;
  if (blk < gbA)
    agg_body<RELU>(srcA, selfA, offA, csrA, WpA, biasA, outA, NA, blk);
  else
    agg_body<RELU>(srcB, selfB, offB, csrB, WpB, biasB, outB, NB, blk - gbA);
}

// ---- edge classifier, EDGE order, unroll x2 -------------------------------
__global__ __launch_bounds__(256) void edge_mlp(
    const unsigned short* __restrict__ pu, const unsigned short* __restrict__ pm,
    const int* __restrict__ u_idx, const int* __restrict__ m_idx,
    const float* __restrict__ w2, const float* __restrict__ bvec,
    float* __restrict__ out, int E) {
  int t = threadIdx.x;
  int lane = t & 63;
  int sub = lane >> 4;   // subgroup 0..3
  int fl = lane & 15;    // position in subgroup
  int f = fl * 4;        // features f..f+3
  int wid = (blockIdx.x * 256 + t) >> 6;
  int nw = (gridDim.x * 256) >> 6;
  float4 wA = reinterpret_cast<const float4*>(w2)[2 * fl];      // rows f, f+1
  float4 wB = reinterpret_cast<const float4*>(w2)[2 * fl + 1];  // rows f+2, f+3
  float ob0 = bvec[0], ob1 = bvec[1];
  int ngrp = (E + 7) >> 3;
  for (int g = wid; g < ngrp; g += nw) {
    int eA = g * 8 + sub, eB = eA + 4;
    bool vA = eA < E, vB = eB < E;
    int exA = vA ? eA : 0, exB = vB ? eB : 0;
    int uA = __builtin_nontemporal_load(&u_idx[exA]);
    int mA = __builtin_nontemporal_load(&m_idx[exA]);
    int uB = __builtin_nontemporal_load(&u_idx[exB]);
    int mB = __builtin_nontemporal_load(&m_idx[exB]);
    ushort4 a4A = *reinterpret_cast<const ushort4*>(&pu[(size_t)uA * 64 + f]);
    ushort4 b4A = *reinterpret_cast<const ushort4*>(&pm[(size_t)mA * 64 + f]);
    ushort4 a4B = *reinterpret_cast<const ushort4*>(&pu[(size_t)uB * 64 + f]);
    ushort4 b4B = *reinterpret_cast<const ushort4*>(&pm[(size_t)mB * 64 + f]);
    float v0 = fmaxf(bf2f(a4A.x) + bf2f(b4A.x), 0.f);
    float v1 = fmaxf(bf2f(a4A.y) + bf2f(b4A.y), 0.f);
    float v2 = fmaxf(bf2f(a4A.z) + bf2f(b4A.z), 0.f);
    float v3 = fmaxf(bf2f(a4A.w) + bf2f(b4A.w), 0.f);
    float p0 = v0 * wA.x + v1 * wA.z + v2 * wB.x + v3 * wB.z;
    float p1 = v0 * wA.y + v1 * wA.w + v2 * wB.y + v3 * wB.w;
    float w0 = fmaxf(bf2f(a4B.x) + bf2f(b4B.x), 0.f);
    float w1 = fmaxf(bf2f(a4B.y) + bf2f(b4B.y), 0.f);
    float w2v = fmaxf(bf2f(a4B.z) + bf2f(b4B.z), 0.f);
    float w3 = fmaxf(bf2f(a4B.w) + bf2f(b4B.w), 0.f);
    float q0 = w0 * wA.x + w1 * wA.z + w2v * wB.x + w3 * wB.z;
    float q1 = w0 * wA.y + w1 * wA.w + w2v * wB.y + w3 * wB.w;
#pragma unroll
    for (int o = 8; o; o >>= 1) {
      p0 += __shfl_xor(p0, o); p1 += __shfl_xor(p1, o);
      q0 += __shfl_xor(q0, o); q1 += __shfl_xor(q1, o);
    }
    if (fl == 0) {
      if (vA) *reinterpret_cast<float2*>(&out[(size_t)eA * 2]) = make_float2(p0 + ob0, p1 + ob1);
      if (vB) *reinterpret_cast<float2*>(&out[(size_t)eB * 2]) = make_float2(q0 + ob0, q1 + ob1);
    }
  }
}

extern "C" void kernel_launch(void* const* d_in, const int* in_sizes, int n_in,
                              void* d_out, int out_size, void* d_ws, size_t ws_size,
                              hipStream_t stream) {
  const float* x_user  = (const float*)d_in[0];
  const float* x_merch = (const float*)d_in[1];
  const float* bases1  = (const float*)d_in[2];
  const float* coeff1  = (const float*)d_in[3];
  const float* root1   = (const float*)d_in[4];
  const float* b1      = (const float*)d_in[5];
  const float* bases2  = (const float*)d_in[6];
  const float* coeff2  = (const float*)d_in[7];
  const float* root2   = (const float*)d_in[8];
  const float* b2      = (const float*)d_in[9];
  const float* w_mlp1  = (const float*)d_in[10];
  const float* b_mlp1  = (const float*)d_in[11];
  const float* w_mlp2  = (const float*)d_in[12];
  const float* b_mlp2  = (const float*)d_in[13];
  const int*   edge_ix = (const int*)d_in[14];

  const int Nu = in_sizes[0] / 64;
  const int Nm = in_sizes[1] / 64;
  const int E  = in_sizes[14] / 2;
  const int* u_idx = edge_ix;
  const int* m_idx = edge_ix + E;

  char* p = (char*)d_ws;
  auto alloc = [&](size_t bytes) -> char* {
    char* r = p;
    p += (bytes + 255) & ~(size_t)255;
    return r;
  };
  int* off_u = (int*)alloc((size_t)(Nu + 1) * 4);
  int* off_m = (int*)alloc((size_t)(Nm + 1) * 4);
  int* part  = (int*)alloc(512 * 4);
  int* csr_u = (int*)alloc((size_t)E * 4);   // merchants grouped by user
  int* csr_m = (int*)alloc((size_t)E * 4);   // users grouped by merchant
  unsigned short* xb_u = (unsigned short*)alloc((size_t)Nu * 64 * 2);  // also stage_m alias; later pu
  unsigned short* xb_m = (unsigned short*)alloc((size_t)Nm * 64 * 2);  // later pm
  unsigned short* h_u  = (unsigned short*)alloc((size_t)Nu * 64 * 2);  // also stage_u alias
  unsigned short* h_m  = (unsigned short*)alloc((size_t)Nm * 64 * 2);  // also hist alias
  float* Wcat1u = (float*)alloc(8192 * 4);
  float* Wcat1m = (float*)alloc(8192 * 4);
  float* Wcat2u = (float*)alloc(8192 * 4);
  float* Wcat2m = (float*)alloc(8192 * 4);
  unsigned short* Wp1u = (unsigned short*)alloc(8192 * 2);
  unsigned short* Wp1m = (unsigned short*)alloc(8192 * 2);
  unsigned short* Wp2u = (unsigned short*)alloc(8192 * 2);
  unsigned short* Wp2m = (unsigned short*)alloc(8192 * 2);
  float* wp2 = (float*)alloc(4096 * 4);
  float* wr2 = (float*)alloc(4096 * 4);
  float* bu2 = (float*)alloc(64 * 4);
  float* bm2 = (float*)alloc(64 * 4);
  if ((size_t)(p - (char*)d_ws) > ws_size) return;

  const int nblk = (E + 2047) / 2048;
  const int nhist = 256 * nblk;
  const int sb = (nhist + 2047) / 2048;
  // aliases (lifetimes: sorts complete before tobf16 / layer-1 agg writes)
  int*  hist_u  = (int*)h_m;
  int*  hist_m  = hist_u + nhist;
  int2* stage_u = (int2*)h_u;
  int2* stage_m = (int2*)xb_u;

  // ---- CSR build (bucket sort) with piggybacked weight prep ----
  sort_hist_mkW1<<<nblk + 16, 256, 0, stream>>>(
      u_idx, m_idx, hist_u, hist_m, E, nblk,
      bases1, coeff1, root1, bases2, coeff2, Wcat1u, Wcat1m, wp2, wr2);
  scanA2_mkW2<<<2 * sb + 16, 256, 0, stream>>>(
      hist_u, hist_m, part, nhist, sb,
      wp2, wr2, root2, w_mlp1, b2, b_mlp1, Wcat2u, Wcat2m, bu2, bm2);
  scanB2_packW4<<<130, 256, 0, stream>>>(
      part, sb, Wcat1u, Wcat1m, Wcat2u, Wcat2m, Wp1u, Wp1m, Wp2u, Wp2m);
  scanC2<<<2 * sb, 256, 0, stream>>>(hist_u, hist_m, part, nhist, sb);
  sort_scatter1<<<nblk, 256, 0, stream>>>(u_idx, m_idx, hist_u, hist_m,
                                          stage_u, stage_m, E, nblk);
  sort_bucket2<<<512, 256, 0, stream>>>(stage_u, hist_u, csr_u, off_u, Nu,
                                        stage_m, hist_m, csr_m, off_m, Nm,
                                        E, nblk);

  // ---- feature tables ----
  tobf16_2<<<1024, 256, 0, stream>>>(x_user, xb_u, Nu * 16, x_merch, xb_m, Nm * 16);

  int gbu = (Nu + 63) / 64, gbm = (Nm + 63) / 64;
  // layer 1 (relu): user-agg (gathers merchants) || merchant-agg (gathers users)
  agg_dual<1><<<gbu + gbm, 256, 0, stream>>>(
      xb_m, xb_u, off_u, csr_u, Wp1u, b1, h_u, Nu, gbu,
      xb_u, xb_m, off_m, csr_m, Wp1m, b1, h_m, Nm);
  // layer 2 fused with edge-MLP left matrix: pm || pu (both only read h_*)
  unsigned short* pm_buf = xb_m;
  unsigned short* pu_buf = xb_u;
  agg_dual<0><<<gbm + gbu, 256, 0, stream>>>(
      h_u, h_m, off_m, csr_m, Wp2m, bm2, pm_buf, Nm, gbm,
      h_m, h_u, off_u, csr_u, Wp2u, bu2, pu_buf, Nu);

  edge_mlp<<<2048, 256, 0, stream>>>(pu_buf, pm_buf, u_idx, m_idx,
                                     w_mlp2, b_mlp2, (float*)d_out, E);
}